// Round 5
// baseline (206.865 us; speedup 1.0000x reference)
//
#include <hip/hip_runtime.h>
#include <stdint.h>

#define NSAMP 1024
#define D 16384
#define WH 128
#define MARGIN 0.3f
#define SCALE 0.08838834764831845f    // 1/sqrt(128)
#define RSCALE 11.313708498984761f    // sqrt(128)
#define MARG 0.03f                    // selection ambiguity margin (d units)
#define NKS 16                        // uniform K-slices per tile (K=1024 each)
#define NTILE 36                      // upper-triangle 128x128 tiles of 8x8 grid

typedef unsigned int uint;
typedef unsigned short ushort_t;

typedef __attribute__((ext_vector_type(8))) short bf16x8;   // 8 bf16 = 4 VGPRs
typedef __attribute__((ext_vector_type(4))) float f32x4;

__device__ __forceinline__ float bf2f(unsigned short b) {
    return __uint_as_float(((uint)b) << 16);
}
__device__ __forceinline__ unsigned short f2bf(float f) {
    uint u = __float_as_uint(f);
    u += 0x7fffu + ((u >> 16) & 1u);   // RNE (data has no NaN)
    return (unsigned short)(u >> 16);
}
__device__ __forceinline__ void gload_lds16(const void* g, void* l) {
    __builtin_amdgcn_global_load_lds(
        (const __attribute__((address_space(1))) uint32_t*)g,
        (__attribute__((address_space(3))) uint32_t*)l, 16, 0, 0);
}
// Swizzled LDS byte offset for a 128-col bf16 row-major tile (k_dc_mfma).
__device__ __forceinline__ int lds_off(int row, int col) {
    return row * 256 + ((((col >> 3) ^ (row & 15)) << 4) | ((col & 7) << 1));
}

// ---------------- kernel 1: row norms (fp32) + hi bf16 cast ----------------
__global__ __launch_bounds__(256) void k_norms_hi(const float* __restrict__ x,
                                                  float* __restrict__ sq,
                                                  ushort_t* __restrict__ xhi) {
    int b = blockIdx.x;
    int tid = threadIdx.x;
    const float* xr = x + (size_t)b * D;
    ushort_t* hr = xhi + (size_t)b * D;
    float s = 0.f;
    #pragma unroll
    for (int m = 0; m < 16; ++m) {
        int e = m * 1024 + tid * 4;
        float4 v = *(const float4*)(xr + e);
        s += v.x * v.x + v.y * v.y + v.z * v.z + v.w * v.w;
        ushort4 h;
        h.x = f2bf(v.x); h.y = f2bf(v.y); h.z = f2bf(v.z); h.w = f2bf(v.w);
        *(ushort4*)(hr + e) = h;
    }
    for (int off = 32; off; off >>= 1) s += __shfl_down(s, off, 64);
    __shared__ float red[4];
    if ((tid & 63) == 0) red[tid >> 6] = s;
    __syncthreads();
    if (tid == 0) sq[b] = red[0] + red[1] + red[2] + red[3];
}

// ---------------- kernel 2: G~ = Hi.Hi^T partials via MFMA ----------------
// Triangle tiles only, UNIFORM K=1024 per block. Flat grid of 576 with
// XCD-aware decode (blocks sharing K-slice ks -> same XCD; its 2 MB
// column-slice of xhi becomes L2-resident).
// Depth-2 pipeline, 3 LDS buffers (48 KB -> 3 blocks/CU residency, >= the
// grid's max 3/CU). ONE barrier per K=32 step. Rotation invariant:
// stage(kb+2) overwrites buf (kb-1)%3, whose reads finished before this
// step's barrier -> write-after-read is barrier-covered by construction.
// Counted vmcnt(4) retires stage(kb) while stage(kb+1) stays in flight.
// Segment swizzle (seg ^= (row>>1)&3) on global source + fragment read.
__global__ __launch_bounds__(256) void k_gram_hi(const ushort_t* __restrict__ xhi,
                                                 float* __restrict__ Gp) {
    int n = blockIdx.x;
    int r8 = n & 7;
    int m = n >> 3;                 // 0..71 = 36*h + t
    int h = m / 36;                 // 0 or 1
    int t = m - 36 * h;             // 0..35
    int ks = r8 + 8 * h;            // 0..15
    int bi = 0, rem = t;
    while (rem >= 8 - bi) { rem -= 8 - bi; ++bi; }
    int bj = bi + rem;
    int i0 = bi * 128, j0 = bj * 128;
    int kstart = ks * (D / NKS);

    int tid = threadIdx.x;
    int w = tid >> 6, lane = tid & 63;
    int wm = w & 1, wn = w >> 1;
    int quad = lane >> 4, m16 = lane & 15;
    int srow = lane >> 2, sseg = lane & 3;
    int swseg = sseg ^ ((srow >> 1) & 3);          // pre-swizzled source seg
    int rsw = (quad ^ ((m16 >> 1) & 3)) << 3;      // lane-constant read seg

    __shared__ __align__(16) ushort_t A_s[3][128 * 32];   // 24 KB
    __shared__ __align__(16) ushort_t B_s[3][128 * 32];   // 24 KB

    f32x4 acc[4][4];
    #pragma unroll
    for (int ii = 0; ii < 4; ++ii)
        #pragma unroll
        for (int jj = 0; jj < 4; ++jj)
            acc[ii][jj] = (f32x4){0.f, 0.f, 0.f, 0.f};

    const size_t Abase = (size_t)i0 * D;
    const size_t Bbase = (size_t)j0 * D;

    auto stage = [&](int s, int bsel) {
        int k0 = kstart + s * 32;
        #pragma unroll
        for (int c = 0; c < 2; ++c) {
            int r = w * 32 + c * 16 + srow;
            size_t go = (size_t)r * D + k0 + swseg * 8;
            int lo = (w * 32 + c * 16) * 32;
            gload_lds16(xhi + Abase + go, &A_s[bsel][lo]);
            gload_lds16(xhi + Bbase + go, &B_s[bsel][lo]);
        }
    };
    auto compute = [&](int bsel) {
        bf16x8 ah[4], bh[4];
        #pragma unroll
        for (int ii = 0; ii < 4; ++ii) {
            int ar = wm * 64 + ii * 16 + m16;
            ah[ii] = *(const bf16x8*)&A_s[bsel][ar * 32 + rsw];
        }
        #pragma unroll
        for (int jj = 0; jj < 4; ++jj) {
            int br = wn * 64 + jj * 16 + m16;
            bh[jj] = *(const bf16x8*)&B_s[bsel][br * 32 + rsw];
        }
        #pragma unroll
        for (int ii = 0; ii < 4; ++ii)
            #pragma unroll
            for (int jj = 0; jj < 4; ++jj)
                acc[ii][jj] = __builtin_amdgcn_mfma_f32_16x16x32_bf16(ah[ii], bh[jj], acc[ii][jj], 0, 0, 0);
    };

    stage(0, 0);
    stage(1, 1);
    int cb = 0, sb = 2;
    for (int kb = 0; kb < 31; ++kb) {
        asm volatile("s_waitcnt vmcnt(4)" ::: "memory");   // retire stage(kb)
        __builtin_amdgcn_sched_barrier(0);
        __builtin_amdgcn_s_barrier();       // buf cb full for all waves; reads
                                            // of buf sb (step kb-1) retired
        if (kb < 30) { stage(kb + 2, sb); sb = (sb == 2) ? 0 : sb + 1; }
        compute(cb);
        cb = (cb == 2) ? 0 : cb + 1;
    }
    asm volatile("s_waitcnt vmcnt(0)" ::: "memory");
    __builtin_amdgcn_sched_barrier(0);
    __builtin_amdgcn_s_barrier();
    compute(cb);                            // kb = 31 -> buf 31 % 3 = 1

    // Uniform partial slot: tile-major so fold reads 1 MB contiguous/tile.
    float* Gb = Gp + ((size_t)(t * NKS + ks) << 14);
    #pragma unroll
    for (int ii = 0; ii < 4; ++ii)
        #pragma unroll
        for (int jj = 0; jj < 4; ++jj) {
            int rg = wm * 64 + ii * 16 + quad * 4;
            int cg = wn * 64 + jj * 16 + m16;
            #pragma unroll
            for (int r = 0; r < 4; ++r)
                Gb[(rg + r) * 128 + cg] = acc[ii][jj][r];
        }
}

// ---------------- kernel 2b: fold triangle partials + mirror ----------
// grid (36 tiles, 4 row-panels). Sums the tile's 16 partial slots, writes
// the upper-triangle region directly (coalesced) and, for off-diag tiles,
// the mirrored region via an LDS transpose (coalesced 16-float runs).
__global__ __launch_bounds__(256) void k_fold_tri(const float* __restrict__ Gp,
                                                  float* __restrict__ G) {
    int t = blockIdx.x;       // 0..35 upper-triangle tile index
    int panel = blockIdx.y;   // 0..3: 32-row panel within the tile
    int bi = 0, rem = t;
    while (rem >= 8 - bi) { rem -= 8 - bi; ++bi; }
    int bj = bi + rem;
    bool diag = (bi == bj);
    int tid = threadIdx.x;

    const float* P = Gp + (((size_t)t * NKS) << 14) + panel * 4096;

    float4 s[4];
    #pragma unroll
    for (int m = 0; m < 4; ++m)
        s[m] = *(const float4*)(P + (tid + 256 * m) * 4);
    #pragma unroll
    for (int p = 1; p < NKS; ++p) {
        const float* Pp = P + (((size_t)p) << 14);
        #pragma unroll
        for (int m = 0; m < 4; ++m) {
            float4 v = *(const float4*)(Pp + (tid + 256 * m) * 4);
            s[m].x += v.x; s[m].y += v.y; s[m].z += v.z; s[m].w += v.w;
        }
    }

    int i0 = bi * 128, j0 = bj * 128, r0 = panel * 32;
    __shared__ float ts[32][129];
    #pragma unroll
    for (int m = 0; m < 4; ++m) {
        int p4 = (tid + 256 * m) * 4;
        int lr = p4 >> 7, lc = p4 & 127;
        *(float4*)(&G[(size_t)(i0 + r0 + lr) * NSAMP + j0 + lc]) = s[m];
        if (!diag) {
            ts[lr][lc] = s[m].x; ts[lr][lc + 1] = s[m].y;
            ts[lr][lc + 2] = s[m].z; ts[lr][lc + 3] = s[m].w;
        }
    }
    if (diag) return;
    __syncthreads();
    int oc = tid >> 1, half = tid & 1;
    float4 o[4];
    #pragma unroll
    for (int k = 0; k < 4; ++k) {
        int rr = half * 16 + k * 4;
        o[k].x = ts[rr][oc]; o[k].y = ts[rr + 1][oc];
        o[k].z = ts[rr + 2][oc]; o[k].w = ts[rr + 3][oc];
    }
    float* Gm = &G[(size_t)(j0 + oc) * NSAMP + i0 + r0 + half * 16];
    #pragma unroll
    for (int k = 0; k < 4; ++k) *(float4*)(Gm + k * 4) = o[k];
}

// ------- kernel 3: select + ambiguity flagging + fused exact re-rank -------
__global__ __launch_bounds__(256) void k_select_fix(const float* __restrict__ G,
                                                    const float* __restrict__ sq,
                                                    const int* __restrict__ tgt,
                                                    const float* __restrict__ x,
                                                    const ushort_t* __restrict__ xhi,
                                                    int* __restrict__ hp,
                                                    int* __restrict__ hn,
                                                    float* __restrict__ dsq) {
    int i = blockIdx.x;
    int tid = threadIdx.x;
    float sqi = sq[i];
    int ti = tgt[i];
    float dloc[4]; bool sloc[4];
    float pv = -3.0e38f; int pj = 0x7FFFFFFF;
    float nv = 3.0e38f;  int nj = 0x7FFFFFFF;
    #pragma unroll
    for (int m = 0; m < 4; ++m) {
        int j = tid + 256 * m;
        float g = G[(size_t)i * NSAMP + j];
        float d = sqrtf(fmaxf(sqi + sq[j] - 2.f * g, 1e-12f));
        bool same = (tgt[j] == ti);
        dloc[m] = d; sloc[m] = same;
        float cp = same ? d : -1e30f;
        float cn = same ? 1e30f : d;
        if (cp > pv || (cp == pv && j < pj)) { pv = cp; pj = j; }
        if (cn < nv || (cn == nv && j < nj)) { nv = cn; nj = j; }
    }
    for (int off = 32; off; off >>= 1) {
        float opv = __shfl_down(pv, off, 64); int opj = __shfl_down(pj, off, 64);
        float onv = __shfl_down(nv, off, 64); int onj = __shfl_down(nj, off, 64);
        if (opv > pv || (opv == pv && opj < pj)) { pv = opv; pj = opj; }
        if (onv < nv || (onv == nv && onj < nj)) { nv = onv; nj = onj; }
    }
    __shared__ float spv[4], snv[4];
    __shared__ int spj[4], snj[4];
    __shared__ float bb[2];
    __shared__ int cc[2];
    if ((tid & 63) == 0) { int wv = tid >> 6; spv[wv] = pv; spj[wv] = pj; snv[wv] = nv; snj[wv] = nj; }
    __syncthreads();
    if (tid == 0) {
        for (int wv = 1; wv < 4; ++wv) {
            if (spv[wv] > pv || (spv[wv] == pv && spj[wv] < pj)) { pv = spv[wv]; pj = spj[wv]; }
            if (snv[wv] < nv || (snv[wv] == nv && snj[wv] < nj)) { nv = snv[wv]; nj = snj[wv]; }
        }
        hp[i] = pj; hn[i] = nj;
        dsq[i] = sqi; dsq[NSAMP + i] = sqi;   // ||A||^2 init for k_dc
        bb[0] = pv; bb[1] = nv;
        cc[0] = 0; cc[1] = 0;
    }
    __syncthreads();
    {
        int lp = 0, ln = 0;
        #pragma unroll
        for (int m = 0; m < 4; ++m) {
            if (sloc[m] && dloc[m] >= bb[0] - MARG) lp++;
            if (!sloc[m] && dloc[m] <= bb[1] + MARG) ln++;
        }
        if (lp) atomicAdd(&cc[0], lp);
        if (ln) atomicAdd(&cc[1], ln);
    }
    __syncthreads();

    __shared__ int cand[32];
    __shared__ int ncand;
    __shared__ float bred[4];
    const float* xi = x + (size_t)i * D;
    const ushort_t* hi = xhi + (size_t)i * D;
    for (int type = 0; type < 2; ++type) {
        if (cc[type] <= 1) continue;          // block-uniform (shared)
        if (tid == 0) ncand = 0;
        __syncthreads();
        float bd = bb[type];
        #pragma unroll
        for (int m = 0; m < 4; ++m) {
            int j = tid + 256 * m;
            bool fl = (type == 0) ? (sloc[m] && dloc[m] >= bd - MARG)
                                  : (!sloc[m] && dloc[m] <= bd + MARG);
            if (fl) { int k = atomicAdd(&ncand, 1); if (k < 32) cand[k] = j; }
        }
        __syncthreads();
        int nc = ncand < 32 ? ncand : 32;
        float bestv = (type == 0) ? -3.0e38f : 3.0e38f;
        int bestj = 0x7FFFFFFF;
        for (int c = 0; c < nc; ++c) {
            int j = cand[c];
            const float* xj = x + (size_t)j * D;
            const ushort_t* hj = xhi + (size_t)j * D;
            float corr = 0.f;
            #pragma unroll
            for (int m = 0; m < 16; ++m) {
                int k = m * 1024 + tid * 4;
                float4 xa = *(const float4*)(xi + k);
                float4 xb = *(const float4*)(xj + k);
                ushort4 ha = *(const ushort4*)(hi + k);
                ushort4 hb = *(const ushort4*)(hj + k);
                float a0 = bf2f(ha.x), a1 = bf2f(ha.y), a2 = bf2f(ha.z), a3 = bf2f(ha.w);
                float b0 = bf2f(hb.x), b1 = bf2f(hb.y), b2 = bf2f(hb.z), b3 = bf2f(hb.w);
                corr += a0 * (xb.x - b0) + (xa.x - a0) * b0;
                corr += a1 * (xb.y - b1) + (xa.y - a1) * b1;
                corr += a2 * (xb.z - b2) + (xa.z - a2) * b2;
                corr += a3 * (xb.w - b3) + (xa.w - a3) * b3;
            }
            for (int off = 32; off; off >>= 1) corr += __shfl_down(corr, off, 64);
            if ((tid & 63) == 0) bred[tid >> 6] = corr;
            __syncthreads();
            float cs = bred[0] + bred[1] + bred[2] + bred[3];
            float g = G[(size_t)i * NSAMP + j];
            float d2 = sqi + sq[j] - 2.f * (g + cs);
            float d = sqrtf(fmaxf(d2, 1e-12f));
            if (type == 0) {
                if (d > bestv || (d == bestv && j < bestj)) { bestv = d; bestj = j; }
            } else {
                if (d < bestv || (d == bestv && j < bestj)) { bestv = d; bestj = j; }
            }
            __syncthreads();
        }
        if (tid == 0 && nc > 0) { if (type == 0) hp[i] = bestj; else hn[i] = bestj; }
        __syncthreads();
    }
}

// ---------------- kernel 4: DC align via MFMA (q-merged) ----------------
// grid (b, which). Each wave handles TWO 16-row tiles (rt = wv, wv+4), so
// the O stage + O transpose run once per block (was twice) and the O/Ot
// fragment ds_reads are shared across both halves.
__global__ __launch_bounds__(256) void k_dc_mfma(const ushort_t* __restrict__ xhi,
                                                 const int* __restrict__ hp,
                                                 const int* __restrict__ hn,
                                                 float* __restrict__ dsq) {
    int b = blockIdx.x;
    int which = blockIdx.y;
    int oidx = (which == 0) ? hp[b] : hn[b];
    const ushort_t* Ag = xhi + (size_t)b * D;
    const ushort_t* Og = xhi + (size_t)oidx * D;

    __shared__ __align__(16) char smem[32768];   // O, then Ot in place

    int tid = threadIdx.x;
    int wv = tid >> 6, lane = tid & 63;
    int quad = lane >> 4, m16 = lane & 15;

    bf16x8 af[2][4];
    #pragma unroll
    for (int h = 0; h < 2; ++h) {
        int rt = h * 4 + wv;
        #pragma unroll
        for (int ks = 0; ks < 4; ++ks)
            af[h][ks] = *(const bf16x8*)(Ag + (rt * 16 + m16) * WH + ks * 32 + quad * 8);
    }

    {
        uint4 stg[8];
        #pragma unroll
        for (int k = 0; k < 8; ++k)
            stg[k] = *(const uint4*)((const char*)Og + (size_t)(tid + 256 * k) * 16);
        #pragma unroll
        for (int k = 0; k < 8; ++k) {
            int g = tid + 256 * k;
            *(uint4*)(smem + lds_off(g >> 4, (g & 15) * 8)) = stg[k];
        }
    }
    __syncthreads();   // B1: O staged

    f32x4 acc[2][8];
    #pragma unroll
    for (int h = 0; h < 2; ++h)
        #pragma unroll
        for (int ti = 0; ti < 8; ++ti)
            acc[h][ti] = (f32x4){0.f, 0.f, 0.f, 0.f};
    #pragma unroll
    for (int ks = 0; ks < 4; ++ks) {
        bf16x8 of[8];
        #pragma unroll
        for (int ti = 0; ti < 8; ++ti)
            of[ti] = *(const bf16x8*)(smem + lds_off(ti * 16 + m16, (ks * 4 + quad) * 8));
        #pragma unroll
        for (int h = 0; h < 2; ++h)
            #pragma unroll
            for (int ti = 0; ti < 8; ++ti)
                acc[h][ti] = __builtin_amdgcn_mfma_f32_16x16x32_bf16(of[ti], af[h][ks], acc[h][ti], 0, 0, 0);
    }

    int c0 = (tid & 31) * 4, h0 = (tid >> 5) * 16;
    uint4 trd[4][2];
    #pragma unroll
    for (int j = 0; j < 4; ++j)
        #pragma unroll
        for (int k = 0; k < 2; ++k)
            trd[j][k] = *(const uint4*)(smem + lds_off(c0 + j, h0 + 8 * k));
    __syncthreads();   // B2: all O reads done

    #pragma unroll
    for (int i = 0; i < 16; ++i) {
        uint v[4];
        #pragma unroll
        for (int j = 0; j < 4; ++j) {
            uint wo = ((const uint*)&trd[j][i >> 3])[(i >> 1) & 3];
            v[j] = (i & 1) ? (wo >> 16) : (wo & 0xffffu);
        }
        uint2 pk;
        pk.x = v[0] | (v[1] << 16);
        pk.y = v[2] | (v[3] << 16);
        *(uint2*)(smem + lds_off(h0 + i, c0)) = pk;
    }

    float tpart[2];
    bf16x8 pf[2][4];
    #pragma unroll
    for (int h = 0; h < 2; ++h) {
        float mx = -3.0e38f;
        #pragma unroll
        for (int ti = 0; ti < 8; ++ti)
            #pragma unroll
            for (int r = 0; r < 4; ++r) {
                float s = acc[h][ti][r] * SCALE;
                acc[h][ti][r] = s;
                mx = fmaxf(mx, s);
            }
        mx = fmaxf(mx, __shfl_xor(mx, 16, 64));
        mx = fmaxf(mx, __shfl_xor(mx, 32, 64));
        float sum = 0.f, tnum = 0.f;
        #pragma unroll
        for (int ti = 0; ti < 8; ++ti)
            #pragma unroll
            for (int r = 0; r < 4; ++r) {
                float s = acc[h][ti][r];
                float e = __expf(s - mx);
                acc[h][ti][r] = e;
                sum += e;
                tnum += s * e;
            }
        sum += __shfl_xor(sum, 16, 64);
        sum += __shfl_xor(sum, 32, 64);
        tnum += __shfl_xor(tnum, 16, 64);
        tnum += __shfl_xor(tnum, 32, 64);
        float inv = 1.f / sum;
        tpart[h] = 0.25f * tnum * inv;

        uint Ep[8][2];
        #pragma unroll
        for (int ti = 0; ti < 8; ++ti) {
            Ep[ti][0] = (uint)f2bf(acc[h][ti][0] * inv) |
                        ((uint)f2bf(acc[h][ti][1] * inv) << 16);
            Ep[ti][1] = (uint)f2bf(acc[h][ti][2] * inv) |
                        ((uint)f2bf(acc[h][ti][3] * inv) << 16);
        }
        int tih = quad >> 1;
        #pragma unroll
        for (int ks = 0; ks < 4; ++ks) {
            union { uint u[4]; bf16x8 v; } fr;
            #pragma unroll
            for (int k = 0; k < 4; ++k) {
                int src = (((quad << 1) + (k >> 1)) & 3) * 16 + m16;
                int a = __shfl((int)Ep[2 * ks + 0][k & 1], src, 64);
                int bsh = __shfl((int)Ep[2 * ks + 1][k & 1], src, 64);
                fr.u[k] = (uint)((tih == 0) ? a : bsh);
            }
            pf[h][ks] = fr.v;
        }
    }
    __syncthreads();   // B3: Ot complete

    #pragma unroll
    for (int h = 0; h < 2; ++h)
        #pragma unroll
        for (int tj = 0; tj < 8; ++tj)
            acc[h][tj] = (f32x4){0.f, 0.f, 0.f, 0.f};
    #pragma unroll
    for (int ks = 0; ks < 4; ++ks) {
        bf16x8 otf[8];
        #pragma unroll
        for (int tj = 0; tj < 8; ++tj)
            otf[tj] = *(const bf16x8*)(smem + lds_off(tj * 16 + m16, (ks * 4 + quad) * 8));
        #pragma unroll
        for (int h = 0; h < 2; ++h)
            #pragma unroll
            for (int tj = 0; tj < 8; ++tj)
                acc[h][tj] = __builtin_amdgcn_mfma_f32_16x16x32_bf16(pf[h][ks], otf[tj], acc[h][tj], 0, 0, 0);
    }

    float part = 0.f;
    #pragma unroll
    for (int h = 0; h < 2; ++h) {
        float m2 = 0.f;
        #pragma unroll
        for (int tj = 0; tj < 8; ++tj)
            #pragma unroll
            for (int r = 0; r < 4; ++r) {
                float mvv = acc[h][tj][r];
                m2 += mvv * mvv;
            }
        part += m2 - 2.f * RSCALE * tpart[h];
    }
    for (int off = 32; off; off >>= 1) part += __shfl_down(part, off, 64);
    if (lane == 0) atomicAdd(&dsq[which * NSAMP + b], part);
}

// ---------------- kernel 5: final loss ----------------
__global__ void k_loss(const float* __restrict__ dsq, float* __restrict__ out) {
    int tid = threadIdx.x;
    float s = 0.f;
    #pragma unroll
    for (int m = 0; m < 4; ++m) {
        int b = tid + 256 * m;
        float ap = sqrtf(fmaxf(dsq[b], 0.f));
        float an = sqrtf(fmaxf(dsq[NSAMP + b], 0.f));
        s += fmaxf(ap - an + MARGIN, 0.f);
    }
    for (int off = 32; off; off >>= 1) s += __shfl_down(s, off, 64);
    __shared__ float red[4];
    if ((tid & 63) == 0) red[tid >> 6] = s;
    __syncthreads();
    if (tid == 0) out[0] = (red[0] + red[1] + red[2] + red[3]) * (1.f / NSAMP);
}

extern "C" void kernel_launch(void* const* d_in, const int* in_sizes, int n_in,
                              void* d_out, int out_size, void* d_ws, size_t ws_size,
                              hipStream_t stream) {
    const float* x = (const float*)d_in[0];
    const int* tgt = (const int*)d_in[1];
    float* out = (float*)d_out;
    char* ws = (char*)d_ws;

    const size_t GPB = (size_t)NTILE * NKS * 65536;  // 36 MB triangle partials
    const size_t XB = (size_t)NSAMP * D * 2;         // 32 MB (xhi)
    const size_t GB1 = (size_t)NSAMP * NSAMP * 4;    // 4 MB G

    float* Gp = (float*)ws;                               // 36 MB
    ushort_t* xhi = (ushort_t*)(ws + GPB);                // 32 MB
    float* G = (float*)(ws + GPB + XB);                   // 4 MB
    char* tail = ws + GPB + XB + GB1;
    float* sq = (float*)tail;                             // 4 KB
    float* dsq = sq + NSAMP;                              // 8 KB
    int* hp = (int*)(dsq + 2 * NSAMP);                    // 4 KB
    int* hn = hp + NSAMP;                                 // 4 KB

    k_norms_hi<<<NSAMP, 256, 0, stream>>>(x, sq, xhi);
    k_gram_hi<<<NKS * NTILE, 256, 0, stream>>>(xhi, Gp);
    k_fold_tri<<<dim3(NTILE, 4), 256, 0, stream>>>(Gp, G);
    k_select_fix<<<NSAMP, 256, 0, stream>>>(G, sq, tgt, x, xhi, hp, hn, dsq);
    k_dc_mfma<<<dim3(NSAMP, 2), 256, 0, stream>>>(xhi, hp, hn, dsq);
    k_loss<<<1, 256, 0, stream>>>(dsq, out);
}

// Round 7
// 204.543 us; speedup vs baseline: 1.0114x; 1.0114x over previous
//
#include <hip/hip_runtime.h>
#include <stdint.h>

#define NSAMP 1024
#define D 16384
#define WH 128
#define MARGIN 0.3f
#define SCALE 0.08838834764831845f    // 1/sqrt(128)
#define RSCALE 11.313708498984761f    // sqrt(128)
#define MARG 0.03f                    // selection ambiguity margin (d units)
#define NKS 16                        // uniform K-slices per tile (K=1024 each)
#define NTILE 36                      // upper-triangle 128x128 tiles of 8x8 grid

typedef unsigned int uint;
typedef unsigned short ushort_t;

typedef __attribute__((ext_vector_type(8))) short bf16x8;   // 8 bf16 = 4 VGPRs
typedef __attribute__((ext_vector_type(4))) float f32x4;

__device__ __forceinline__ float bf2f(unsigned short b) {
    return __uint_as_float(((uint)b) << 16);
}
__device__ __forceinline__ unsigned short f2bf(float f) {
    uint u = __float_as_uint(f);
    u += 0x7fffu + ((u >> 16) & 1u);   // RNE (data has no NaN)
    return (unsigned short)(u >> 16);
}
__device__ __forceinline__ void gload_lds16(const void* g, void* l) {
    __builtin_amdgcn_global_load_lds(
        (const __attribute__((address_space(1))) uint32_t*)g,
        (__attribute__((address_space(3))) uint32_t*)l, 16, 0, 0);
}
// Swizzled LDS byte offset for a 128-col bf16 row-major tile (k_dc_mfma).
__device__ __forceinline__ int lds_off(int row, int col) {
    return row * 256 + ((((col >> 3) ^ (row & 15)) << 4) | ((col & 7) << 1));
}

// ---------------- kernel 1: row norms (fp32) + hi bf16 cast ----------------
__global__ __launch_bounds__(256) void k_norms_hi(const float* __restrict__ x,
                                                  float* __restrict__ sq,
                                                  ushort_t* __restrict__ xhi) {
    int b = blockIdx.x;
    int tid = threadIdx.x;
    const float* xr = x + (size_t)b * D;
    ushort_t* hr = xhi + (size_t)b * D;
    float s = 0.f;
    #pragma unroll
    for (int m = 0; m < 16; ++m) {
        int e = m * 1024 + tid * 4;
        float4 v = *(const float4*)(xr + e);
        s += v.x * v.x + v.y * v.y + v.z * v.z + v.w * v.w;
        ushort4 h;
        h.x = f2bf(v.x); h.y = f2bf(v.y); h.z = f2bf(v.z); h.w = f2bf(v.w);
        *(ushort4*)(hr + e) = h;
    }
    for (int off = 32; off; off >>= 1) s += __shfl_down(s, off, 64);
    __shared__ float red[4];
    if ((tid & 63) == 0) red[tid >> 6] = s;
    __syncthreads();
    if (tid == 0) sq[b] = red[0] + red[1] + red[2] + red[3];
}

// ---------------- kernel 2: G~ = Hi.Hi^T partials via MFMA ----------------
// Triangle tiles only, UNIFORM K=1024 per block. Flat grid of 576 with
// XCD-aware decode (blocks sharing K-slice ks -> same XCD; its 2 MB
// column-slice of xhi becomes L2-resident).
// R2-PROVEN structure (measured 40.4 us): 2-buffer 32 KB LDS (5 blocks/CU),
// stage(buf^1, kb+1) issued BEFORE compute(buf), one __syncthreads per
// K=32 step. R3/R4/R5 proved deeper pipelines/counted-vmcnt all regress
// here (occupancy loss > latency cover). T5 setprio wraps the MFMA
// cluster (independent blocks sit at different phases on a CU).
// Segment swizzle (seg ^= (row>>1)&3) on global source + fragment read.
__global__ __launch_bounds__(256) void k_gram_hi(const ushort_t* __restrict__ xhi,
                                                 float* __restrict__ Gp) {
    int n = blockIdx.x;
    int r8 = n & 7;
    int m = n >> 3;                 // 0..71 = 36*h + t
    int h = m / 36;                 // 0 or 1
    int t = m - 36 * h;             // 0..35
    int ks = r8 + 8 * h;            // 0..15
    int bi = 0, rem = t;
    while (rem >= 8 - bi) { rem -= 8 - bi; ++bi; }
    int bj = bi + rem;
    int i0 = bi * 128, j0 = bj * 128;
    int kstart = ks * (D / NKS);

    int tid = threadIdx.x;
    int w = tid >> 6, lane = tid & 63;
    int wm = w & 1, wn = w >> 1;
    int quad = lane >> 4, m16 = lane & 15;
    int srow = lane >> 2, sseg = lane & 3;
    int swseg = sseg ^ ((srow >> 1) & 3);          // pre-swizzled source seg
    int rsw = (quad ^ ((m16 >> 1) & 3)) << 3;      // lane-constant read seg

    __shared__ __align__(16) ushort_t A_s[2][128 * 32];   // 16 KB
    __shared__ __align__(16) ushort_t B_s[2][128 * 32];   // 16 KB

    f32x4 acc[4][4];
    #pragma unroll
    for (int ii = 0; ii < 4; ++ii)
        #pragma unroll
        for (int jj = 0; jj < 4; ++jj)
            acc[ii][jj] = (f32x4){0.f, 0.f, 0.f, 0.f};

    const size_t Abase = (size_t)i0 * D;
    const size_t Bbase = (size_t)j0 * D;

    auto stage = [&](int bsel, int k0) {
        #pragma unroll
        for (int c = 0; c < 2; ++c) {
            int r = w * 32 + c * 16 + srow;
            size_t go = (size_t)r * D + k0 + swseg * 8;
            int lo = (w * 32 + c * 16) * 32;
            gload_lds16(xhi + Abase + go, &A_s[bsel][lo]);
            gload_lds16(xhi + Bbase + go, &B_s[bsel][lo]);
        }
    };
    auto compute = [&](int bsel) {
        bf16x8 ah[4], bh[4];
        #pragma unroll
        for (int ii = 0; ii < 4; ++ii) {
            int ar = wm * 64 + ii * 16 + m16;
            ah[ii] = *(const bf16x8*)&A_s[bsel][ar * 32 + rsw];
        }
        #pragma unroll
        for (int jj = 0; jj < 4; ++jj) {
            int br = wn * 64 + jj * 16 + m16;
            bh[jj] = *(const bf16x8*)&B_s[bsel][br * 32 + rsw];
        }
        __builtin_amdgcn_s_setprio(1);
        #pragma unroll
        for (int ii = 0; ii < 4; ++ii)
            #pragma unroll
            for (int jj = 0; jj < 4; ++jj)
                acc[ii][jj] = __builtin_amdgcn_mfma_f32_16x16x32_bf16(ah[ii], bh[jj], acc[ii][jj], 0, 0, 0);
        __builtin_amdgcn_s_setprio(0);
    };

    stage(0, kstart);
    __syncthreads();
    int buf = 0;
    for (int kb = 0; kb < 32; ++kb) {
        if (kb < 31) stage(buf ^ 1, kstart + (kb + 1) * 32);
        compute(buf);
        __syncthreads();
        buf ^= 1;
    }

    // Uniform partial slot: tile-major so fold reads 1 MB contiguous/tile.
    float* Gb = Gp + ((size_t)(t * NKS + ks) << 14);
    #pragma unroll
    for (int ii = 0; ii < 4; ++ii)
        #pragma unroll
        for (int jj = 0; jj < 4; ++jj) {
            int rg = wm * 64 + ii * 16 + quad * 4;
            int cg = wn * 64 + jj * 16 + m16;
            #pragma unroll
            for (int r = 0; r < 4; ++r)
                Gb[(rg + r) * 128 + cg] = acc[ii][jj][r];
        }
}

// ---------------- kernel 2b: fold triangle partials + mirror ----------
// grid (36 tiles, 4 row-panels). Sums the tile's 16 partial slots, writes
// the upper-triangle region directly (coalesced) and, for off-diag tiles,
// the mirrored region via an LDS transpose (coalesced 16-float runs).
__global__ __launch_bounds__(256) void k_fold_tri(const float* __restrict__ Gp,
                                                  float* __restrict__ G) {
    int t = blockIdx.x;       // 0..35 upper-triangle tile index
    int panel = blockIdx.y;   // 0..3: 32-row panel within the tile
    int bi = 0, rem = t;
    while (rem >= 8 - bi) { rem -= 8 - bi; ++bi; }
    int bj = bi + rem;
    bool diag = (bi == bj);
    int tid = threadIdx.x;

    const float* P = Gp + (((size_t)t * NKS) << 14) + panel * 4096;

    float4 s[4];
    #pragma unroll
    for (int m = 0; m < 4; ++m)
        s[m] = *(const float4*)(P + (tid + 256 * m) * 4);
    #pragma unroll
    for (int p = 1; p < NKS; ++p) {
        const float* Pp = P + (((size_t)p) << 14);
        #pragma unroll
        for (int m = 0; m < 4; ++m) {
            float4 v = *(const float4*)(Pp + (tid + 256 * m) * 4);
            s[m].x += v.x; s[m].y += v.y; s[m].z += v.z; s[m].w += v.w;
        }
    }

    int i0 = bi * 128, j0 = bj * 128, r0 = panel * 32;
    __shared__ float ts[32][129];
    #pragma unroll
    for (int m = 0; m < 4; ++m) {
        int p4 = (tid + 256 * m) * 4;
        int lr = p4 >> 7, lc = p4 & 127;
        *(float4*)(&G[(size_t)(i0 + r0 + lr) * NSAMP + j0 + lc]) = s[m];
        if (!diag) {
            ts[lr][lc] = s[m].x; ts[lr][lc + 1] = s[m].y;
            ts[lr][lc + 2] = s[m].z; ts[lr][lc + 3] = s[m].w;
        }
    }
    if (diag) return;
    __syncthreads();
    int oc = tid >> 1, half = tid & 1;
    float4 o[4];
    #pragma unroll
    for (int k = 0; k < 4; ++k) {
        int rr = half * 16 + k * 4;
        o[k].x = ts[rr][oc]; o[k].y = ts[rr + 1][oc];
        o[k].z = ts[rr + 2][oc]; o[k].w = ts[rr + 3][oc];
    }
    float* Gm = &G[(size_t)(j0 + oc) * NSAMP + i0 + r0 + half * 16];
    #pragma unroll
    for (int k = 0; k < 4; ++k) *(float4*)(Gm + k * 4) = o[k];
}

// ------- kernel 3: select + ambiguity flagging + fused exact re-rank -------
__global__ __launch_bounds__(256) void k_select_fix(const float* __restrict__ G,
                                                    const float* __restrict__ sq,
                                                    const int* __restrict__ tgt,
                                                    const float* __restrict__ x,
                                                    const ushort_t* __restrict__ xhi,
                                                    int* __restrict__ hp,
                                                    int* __restrict__ hn,
                                                    float* __restrict__ dsq) {
    int i = blockIdx.x;
    int tid = threadIdx.x;
    float sqi = sq[i];
    int ti = tgt[i];
    float dloc[4]; bool sloc[4];
    float pv = -3.0e38f; int pj = 0x7FFFFFFF;
    float nv = 3.0e38f;  int nj = 0x7FFFFFFF;
    #pragma unroll
    for (int m = 0; m < 4; ++m) {
        int j = tid + 256 * m;
        float g = G[(size_t)i * NSAMP + j];
        float d = sqrtf(fmaxf(sqi + sq[j] - 2.f * g, 1e-12f));
        bool same = (tgt[j] == ti);
        dloc[m] = d; sloc[m] = same;
        float cp = same ? d : -1e30f;
        float cn = same ? 1e30f : d;
        if (cp > pv || (cp == pv && j < pj)) { pv = cp; pj = j; }
        if (cn < nv || (cn == nv && j < nj)) { nv = cn; nj = j; }
    }
    for (int off = 32; off; off >>= 1) {
        float opv = __shfl_down(pv, off, 64); int opj = __shfl_down(pj, off, 64);
        float onv = __shfl_down(nv, off, 64); int onj = __shfl_down(nj, off, 64);
        if (opv > pv || (opv == pv && opj < pj)) { pv = opv; pj = opj; }
        if (onv < nv || (onv == nv && onj < nj)) { nv = onv; nj = onj; }
    }
    __shared__ float spv[4], snv[4];
    __shared__ int spj[4], snj[4];
    __shared__ float bb[2];
    __shared__ int cc[2];
    if ((tid & 63) == 0) { int wv = tid >> 6; spv[wv] = pv; spj[wv] = pj; snv[wv] = nv; snj[wv] = nj; }
    __syncthreads();
    if (tid == 0) {
        for (int wv = 1; wv < 4; ++wv) {
            if (spv[wv] > pv || (spv[wv] == pv && spj[wv] < pj)) { pv = spv[wv]; pj = spj[wv]; }
            if (snv[wv] < nv || (snv[wv] == nv && snj[wv] < nj)) { nv = snv[wv]; nj = snj[wv]; }
        }
        hp[i] = pj; hn[i] = nj;
        dsq[i] = sqi; dsq[NSAMP + i] = sqi;   // ||A||^2 init for k_dc
        bb[0] = pv; bb[1] = nv;
        cc[0] = 0; cc[1] = 0;
    }
    __syncthreads();
    {
        int lp = 0, ln = 0;
        #pragma unroll
        for (int m = 0; m < 4; ++m) {
            if (sloc[m] && dloc[m] >= bb[0] - MARG) lp++;
            if (!sloc[m] && dloc[m] <= bb[1] + MARG) ln++;
        }
        if (lp) atomicAdd(&cc[0], lp);
        if (ln) atomicAdd(&cc[1], ln);
    }
    __syncthreads();

    __shared__ int cand[32];
    __shared__ int ncand;
    __shared__ float bred[4];
    const float* xi = x + (size_t)i * D;
    const ushort_t* hi = xhi + (size_t)i * D;
    for (int type = 0; type < 2; ++type) {
        if (cc[type] <= 1) continue;          // block-uniform (shared)
        if (tid == 0) ncand = 0;
        __syncthreads();
        float bd = bb[type];
        #pragma unroll
        for (int m = 0; m < 4; ++m) {
            int j = tid + 256 * m;
            bool fl = (type == 0) ? (sloc[m] && dloc[m] >= bd - MARG)
                                  : (!sloc[m] && dloc[m] <= bd + MARG);
            if (fl) { int k = atomicAdd(&ncand, 1); if (k < 32) cand[k] = j; }
        }
        __syncthreads();
        int nc = ncand < 32 ? ncand : 32;
        float bestv = (type == 0) ? -3.0e38f : 3.0e38f;
        int bestj = 0x7FFFFFFF;
        for (int c = 0; c < nc; ++c) {
            int j = cand[c];
            const float* xj = x + (size_t)j * D;
            const ushort_t* hj = xhi + (size_t)j * D;
            float corr = 0.f;
            #pragma unroll
            for (int m = 0; m < 16; ++m) {
                int k = m * 1024 + tid * 4;
                float4 xa = *(const float4*)(xi + k);
                float4 xb = *(const float4*)(xj + k);
                ushort4 ha = *(const ushort4*)(hi + k);
                ushort4 hb = *(const ushort4*)(hj + k);
                float a0 = bf2f(ha.x), a1 = bf2f(ha.y), a2 = bf2f(ha.z), a3 = bf2f(ha.w);
                float b0 = bf2f(hb.x), b1 = bf2f(hb.y), b2 = bf2f(hb.z), b3 = bf2f(hb.w);
                corr += a0 * (xb.x - b0) + (xa.x - a0) * b0;
                corr += a1 * (xb.y - b1) + (xa.y - a1) * b1;
                corr += a2 * (xb.z - b2) + (xa.z - a2) * b2;
                corr += a3 * (xb.w - b3) + (xa.w - a3) * b3;
            }
            for (int off = 32; off; off >>= 1) corr += __shfl_down(corr, off, 64);
            if ((tid & 63) == 0) bred[tid >> 6] = corr;
            __syncthreads();
            float cs = bred[0] + bred[1] + bred[2] + bred[3];
            float g = G[(size_t)i * NSAMP + j];
            float d2 = sqi + sq[j] - 2.f * (g + cs);
            float d = sqrtf(fmaxf(d2, 1e-12f));
            if (type == 0) {
                if (d > bestv || (d == bestv && j < bestj)) { bestv = d; bestj = j; }
            } else {
                if (d < bestv || (d == bestv && j < bestj)) { bestv = d; bestj = j; }
            }
            __syncthreads();
        }
        if (tid == 0 && nc > 0) { if (type == 0) hp[i] = bestj; else hn[i] = bestj; }
        __syncthreads();
    }
}

// ---------------- kernel 4: DC align via MFMA (which-merged) --------------
// grid (1024): one block per sample handles BOTH pos and neg in a loop.
// A fragments loaded once. O staged via global_load_lds with PRE-SWIZZLED
// SOURCE: LDS dest is linear (granule p -> byte p*16), source granule is
// the lds_off inverse (s ^ (row&15)), so reads via lds_off() see the same
// swizzled layout with zero staging registers / ds_writes.
__global__ __launch_bounds__(256) void k_dc_mfma(const ushort_t* __restrict__ xhi,
                                                 const int* __restrict__ hp,
                                                 const int* __restrict__ hn,
                                                 float* __restrict__ dsq) {
    int b = blockIdx.x;
    const ushort_t* Ag = xhi + (size_t)b * D;
    int oidx[2] = {hp[b], hn[b]};

    __shared__ __align__(16) char smem[32768];   // O, then Ot in place

    int tid = threadIdx.x;
    int wv = tid >> 6, lane = tid & 63;
    int quad = lane >> 4, m16 = lane & 15;

    bf16x8 af[2][4];
    #pragma unroll
    for (int h = 0; h < 2; ++h) {
        int rt = h * 4 + wv;
        #pragma unroll
        for (int ks = 0; ks < 4; ++ks)
            af[h][ks] = *(const bf16x8*)(Ag + (rt * 16 + m16) * WH + ks * 32 + quad * 8);
    }

    // Pre-swizzled async O staging: granule p = tid + 256*k; LDS dest
    // linear p*16; source element (p>>4)*128 + ((p&15)^((p>>4)&15))*8.
    auto stage_O = [&](const ushort_t* Og) {
        #pragma unroll
        for (int k = 0; k < 8; ++k) {
            int p = tid + 256 * k;
            int row = p >> 4, s = p & 15;
            gload_lds16(Og + row * 128 + ((s ^ (row & 15)) << 3),
                        smem + p * 16);
        }
    };

    stage_O(xhi + (size_t)oidx[0] * D);
    __syncthreads();   // B1: O staged (syncthreads drains vmcnt)

    for (int which = 0; which < 2; ++which) {
        f32x4 acc[2][8];
        #pragma unroll
        for (int h = 0; h < 2; ++h)
            #pragma unroll
            for (int ti = 0; ti < 8; ++ti)
                acc[h][ti] = (f32x4){0.f, 0.f, 0.f, 0.f};
        #pragma unroll
        for (int ks = 0; ks < 4; ++ks) {
            bf16x8 of[8];
            #pragma unroll
            for (int ti = 0; ti < 8; ++ti)
                of[ti] = *(const bf16x8*)(smem + lds_off(ti * 16 + m16, (ks * 4 + quad) * 8));
            __builtin_amdgcn_s_setprio(1);
            #pragma unroll
            for (int h = 0; h < 2; ++h)
                #pragma unroll
                for (int ti = 0; ti < 8; ++ti)
                    acc[h][ti] = __builtin_amdgcn_mfma_f32_16x16x32_bf16(of[ti], af[h][ks], acc[h][ti], 0, 0, 0);
            __builtin_amdgcn_s_setprio(0);
        }

        int c0 = (tid & 31) * 4, h0 = (tid >> 5) * 16;
        uint4 trd[4][2];
        #pragma unroll
        for (int j = 0; j < 4; ++j)
            #pragma unroll
            for (int k = 0; k < 2; ++k)
                trd[j][k] = *(const uint4*)(smem + lds_off(c0 + j, h0 + 8 * k));
        __syncthreads();   // B2: all O reads done

        #pragma unroll
        for (int i = 0; i < 16; ++i) {
            uint v[4];
            #pragma unroll
            for (int j = 0; j < 4; ++j) {
                uint wo = ((const uint*)&trd[j][i >> 3])[(i >> 1) & 3];
                v[j] = (i & 1) ? (wo >> 16) : (wo & 0xffffu);
            }
            uint2 pk;
            pk.x = v[0] | (v[1] << 16);
            pk.y = v[2] | (v[3] << 16);
            *(uint2*)(smem + lds_off(h0 + i, c0)) = pk;
        }

        float tpart[2];
        bf16x8 pf[2][4];
        #pragma unroll
        for (int h = 0; h < 2; ++h) {
            float mx = -3.0e38f;
            #pragma unroll
            for (int ti = 0; ti < 8; ++ti)
                #pragma unroll
                for (int r = 0; r < 4; ++r) {
                    float s = acc[h][ti][r] * SCALE;
                    acc[h][ti][r] = s;
                    mx = fmaxf(mx, s);
                }
            mx = fmaxf(mx, __shfl_xor(mx, 16, 64));
            mx = fmaxf(mx, __shfl_xor(mx, 32, 64));
            float sum = 0.f, tnum = 0.f;
            #pragma unroll
            for (int ti = 0; ti < 8; ++ti)
                #pragma unroll
                for (int r = 0; r < 4; ++r) {
                    float s = acc[h][ti][r];
                    float e = __expf(s - mx);
                    acc[h][ti][r] = e;
                    sum += e;
                    tnum += s * e;
                }
            sum += __shfl_xor(sum, 16, 64);
            sum += __shfl_xor(sum, 32, 64);
            tnum += __shfl_xor(tnum, 16, 64);
            tnum += __shfl_xor(tnum, 32, 64);
            float inv = 1.f / sum;
            tpart[h] = 0.25f * tnum * inv;

            uint Ep[8][2];
            #pragma unroll
            for (int ti = 0; ti < 8; ++ti) {
                Ep[ti][0] = (uint)f2bf(acc[h][ti][0] * inv) |
                            ((uint)f2bf(acc[h][ti][1] * inv) << 16);
                Ep[ti][1] = (uint)f2bf(acc[h][ti][2] * inv) |
                            ((uint)f2bf(acc[h][ti][3] * inv) << 16);
            }
            int tih = quad >> 1;
            #pragma unroll
            for (int ks = 0; ks < 4; ++ks) {
                union { uint u[4]; bf16x8 v; } fr;
                #pragma unroll
                for (int k = 0; k < 4; ++k) {
                    int src = (((quad << 1) + (k >> 1)) & 3) * 16 + m16;
                    int a = __shfl((int)Ep[2 * ks + 0][k & 1], src, 64);
                    int bsh = __shfl((int)Ep[2 * ks + 1][k & 1], src, 64);
                    fr.u[k] = (uint)((tih == 0) ? a : bsh);
                }
                pf[h][ks] = fr.v;
            }
        }
        __syncthreads();   // B3: Ot complete

        #pragma unroll
        for (int h = 0; h < 2; ++h)
            #pragma unroll
            for (int tj = 0; tj < 8; ++tj)
                acc[h][tj] = (f32x4){0.f, 0.f, 0.f, 0.f};
        #pragma unroll
        for (int ks = 0; ks < 4; ++ks) {
            bf16x8 otf[8];
            #pragma unroll
            for (int tj = 0; tj < 8; ++tj)
                otf[tj] = *(const bf16x8*)(smem + lds_off(tj * 16 + m16, (ks * 4 + quad) * 8));
            __builtin_amdgcn_s_setprio(1);
            #pragma unroll
            for (int h = 0; h < 2; ++h)
                #pragma unroll
                for (int tj = 0; tj < 8; ++tj)
                    acc[h][tj] = __builtin_amdgcn_mfma_f32_16x16x32_bf16(pf[h][ks], otf[tj], acc[h][tj], 0, 0, 0);
            __builtin_amdgcn_s_setprio(0);
        }

        float part = 0.f;
        #pragma unroll
        for (int h = 0; h < 2; ++h) {
            float m2 = 0.f;
            #pragma unroll
            for (int tj = 0; tj < 8; ++tj)
                #pragma unroll
                for (int r = 0; r < 4; ++r) {
                    float mvv = acc[h][tj][r];
                    m2 += mvv * mvv;
                }
            part += m2 - 2.f * RSCALE * tpart[h];
        }
        for (int off = 32; off; off >>= 1) part += __shfl_down(part, off, 64);
        if (lane == 0) atomicAdd(&dsq[which * NSAMP + b], part);

        if (which == 0) {
            __syncthreads();   // B4: all Ot reads done; smem reusable
            stage_O(xhi + (size_t)oidx[1] * D);
            __syncthreads();   // B5: O1 staged (drains vmcnt)
        }
    }
}

// ---------------- kernel 5: final loss ----------------
__global__ void k_loss(const float* __restrict__ dsq, float* __restrict__ out) {
    int tid = threadIdx.x;
    float s = 0.f;
    #pragma unroll
    for (int m = 0; m < 4; ++m) {
        int b = tid + 256 * m;
        float ap = sqrtf(fmaxf(dsq[b], 0.f));
        float an = sqrtf(fmaxf(dsq[NSAMP + b], 0.f));
        s += fmaxf(ap - an + MARGIN, 0.f);
    }
    for (int off = 32; off; off >>= 1) s += __shfl_down(s, off, 64);
    __shared__ float red[4];
    if ((tid & 63) == 0) red[tid >> 6] = s;
    __syncthreads();
    if (tid == 0) out[0] = (red[0] + red[1] + red[2] + red[3]) * (1.f / NSAMP);
}

extern "C" void kernel_launch(void* const* d_in, const int* in_sizes, int n_in,
                              void* d_out, int out_size, void* d_ws, size_t ws_size,
                              hipStream_t stream) {
    const float* x = (const float*)d_in[0];
    const int* tgt = (const int*)d_in[1];
    float* out = (float*)d_out;
    char* ws = (char*)d_ws;

    const size_t GPB = (size_t)NTILE * NKS * 65536;  // 36 MB triangle partials
    const size_t XB = (size_t)NSAMP * D * 2;         // 32 MB (xhi)
    const size_t GB1 = (size_t)NSAMP * NSAMP * 4;    // 4 MB G

    float* Gp = (float*)ws;                               // 36 MB
    ushort_t* xhi = (ushort_t*)(ws + GPB);                // 32 MB
    float* G = (float*)(ws + GPB + XB);                   // 4 MB
    char* tail = ws + GPB + XB + GB1;
    float* sq = (float*)tail;                             // 4 KB
    float* dsq = sq + NSAMP;                              // 8 KB
    int* hp = (int*)(dsq + 2 * NSAMP);                    // 4 KB
    int* hn = hp + NSAMP;                                 // 4 KB

    k_norms_hi<<<NSAMP, 256, 0, stream>>>(x, sq, xhi);
    k_gram_hi<<<NKS * NTILE, 256, 0, stream>>>(xhi, Gp);
    k_fold_tri<<<dim3(NTILE, 4), 256, 0, stream>>>(Gp, G);
    k_select_fix<<<NSAMP, 256, 0, stream>>>(G, sq, tgt, x, xhi, hp, hn, dsq);
    k_dc_mfma<<<NSAMP, 256, 0, stream>>>(xhi, hp, hn, dsq);
    k_loss<<<1, 256, 0, stream>>>(dsq, out);
}

// Round 8
// 194.215 us; speedup vs baseline: 1.0651x; 1.0532x over previous
//
#include <hip/hip_runtime.h>
#include <stdint.h>

#define NSAMP 1024
#define D 16384
#define WH 128
#define MARGIN 0.3f
#define SCALE 0.08838834764831845f    // 1/sqrt(128)
#define RSCALE 11.313708498984761f    // sqrt(128)
#define MARG 0.03f                    // selection ambiguity margin (d units)
#define NKS 16                        // uniform K-slices per tile (K=1024 each)
#define NTILE 36                      // upper-triangle 128x128 tiles of 8x8 grid

typedef unsigned int uint;
typedef unsigned short ushort_t;

typedef __attribute__((ext_vector_type(8))) short bf16x8;   // 8 bf16 = 4 VGPRs
typedef __attribute__((ext_vector_type(4))) float f32x4;

__device__ __forceinline__ float bf2f(unsigned short b) {
    return __uint_as_float(((uint)b) << 16);
}
__device__ __forceinline__ unsigned short f2bf(float f) {
    uint u = __float_as_uint(f);
    u += 0x7fffu + ((u >> 16) & 1u);   // RNE (data has no NaN)
    return (unsigned short)(u >> 16);
}
__device__ __forceinline__ void gload_lds16(const void* g, void* l) {
    __builtin_amdgcn_global_load_lds(
        (const __attribute__((address_space(1))) uint32_t*)g,
        (__attribute__((address_space(3))) uint32_t*)l, 16, 0, 0);
}
// Swizzled LDS byte offset for a 128-col bf16 row-major tile (k_dc_mfma).
__device__ __forceinline__ int lds_off(int row, int col) {
    return row * 256 + ((((col >> 3) ^ (row & 15)) << 4) | ((col & 7) << 1));
}

// ---------------- kernel 1: row norms (fp32) + hi bf16 cast ----------------
__global__ __launch_bounds__(256) void k_norms_hi(const float* __restrict__ x,
                                                  float* __restrict__ sq,
                                                  ushort_t* __restrict__ xhi) {
    int b = blockIdx.x;
    int tid = threadIdx.x;
    const float* xr = x + (size_t)b * D;
    ushort_t* hr = xhi + (size_t)b * D;
    float s = 0.f;
    #pragma unroll
    for (int m = 0; m < 16; ++m) {
        int e = m * 1024 + tid * 4;
        float4 v = *(const float4*)(xr + e);
        s += v.x * v.x + v.y * v.y + v.z * v.z + v.w * v.w;
        ushort4 h;
        h.x = f2bf(v.x); h.y = f2bf(v.y); h.z = f2bf(v.z); h.w = f2bf(v.w);
        *(ushort4*)(hr + e) = h;
    }
    for (int off = 32; off; off >>= 1) s += __shfl_down(s, off, 64);
    __shared__ float red[4];
    if ((tid & 63) == 0) red[tid >> 6] = s;
    __syncthreads();
    if (tid == 0) sq[b] = red[0] + red[1] + red[2] + red[3];
}

// ---------------- kernel 2: G~ = Hi.Hi^T partials via MFMA ----------------
// FROZEN (best measured ~37 us inferred from R7 wall): R2 2-barrier
// structure + XCD-aware flat decode + T5 setprio. R3/R4/R5 proved deeper
// pipelines / counted-vmcnt all regress here.
__global__ __launch_bounds__(256) void k_gram_hi(const ushort_t* __restrict__ xhi,
                                                 float* __restrict__ Gp) {
    int n = blockIdx.x;
    int r8 = n & 7;
    int m = n >> 3;                 // 0..71 = 36*h + t
    int h = m / 36;                 // 0 or 1
    int t = m - 36 * h;             // 0..35
    int ks = r8 + 8 * h;            // 0..15
    int bi = 0, rem = t;
    while (rem >= 8 - bi) { rem -= 8 - bi; ++bi; }
    int bj = bi + rem;
    int i0 = bi * 128, j0 = bj * 128;
    int kstart = ks * (D / NKS);

    int tid = threadIdx.x;
    int w = tid >> 6, lane = tid & 63;
    int wm = w & 1, wn = w >> 1;
    int quad = lane >> 4, m16 = lane & 15;
    int srow = lane >> 2, sseg = lane & 3;
    int swseg = sseg ^ ((srow >> 1) & 3);          // pre-swizzled source seg
    int rsw = (quad ^ ((m16 >> 1) & 3)) << 3;      // lane-constant read seg

    __shared__ __align__(16) ushort_t A_s[2][128 * 32];   // 16 KB
    __shared__ __align__(16) ushort_t B_s[2][128 * 32];   // 16 KB

    f32x4 acc[4][4];
    #pragma unroll
    for (int ii = 0; ii < 4; ++ii)
        #pragma unroll
        for (int jj = 0; jj < 4; ++jj)
            acc[ii][jj] = (f32x4){0.f, 0.f, 0.f, 0.f};

    const size_t Abase = (size_t)i0 * D;
    const size_t Bbase = (size_t)j0 * D;

    auto stage = [&](int bsel, int k0) {
        #pragma unroll
        for (int c = 0; c < 2; ++c) {
            int r = w * 32 + c * 16 + srow;
            size_t go = (size_t)r * D + k0 + swseg * 8;
            int lo = (w * 32 + c * 16) * 32;
            gload_lds16(xhi + Abase + go, &A_s[bsel][lo]);
            gload_lds16(xhi + Bbase + go, &B_s[bsel][lo]);
        }
    };
    auto compute = [&](int bsel) {
        bf16x8 ah[4], bh[4];
        #pragma unroll
        for (int ii = 0; ii < 4; ++ii) {
            int ar = wm * 64 + ii * 16 + m16;
            ah[ii] = *(const bf16x8*)&A_s[bsel][ar * 32 + rsw];
        }
        #pragma unroll
        for (int jj = 0; jj < 4; ++jj) {
            int br = wn * 64 + jj * 16 + m16;
            bh[jj] = *(const bf16x8*)&B_s[bsel][br * 32 + rsw];
        }
        __builtin_amdgcn_s_setprio(1);
        #pragma unroll
        for (int ii = 0; ii < 4; ++ii)
            #pragma unroll
            for (int jj = 0; jj < 4; ++jj)
                acc[ii][jj] = __builtin_amdgcn_mfma_f32_16x16x32_bf16(ah[ii], bh[jj], acc[ii][jj], 0, 0, 0);
        __builtin_amdgcn_s_setprio(0);
    };

    stage(0, kstart);
    __syncthreads();
    int buf = 0;
    for (int kb = 0; kb < 32; ++kb) {
        if (kb < 31) stage(buf ^ 1, kstart + (kb + 1) * 32);
        compute(buf);
        __syncthreads();
        buf ^= 1;
    }

    // Uniform partial slot: tile-major so fold reads 1 MB contiguous/tile.
    float* Gb = Gp + ((size_t)(t * NKS + ks) << 14);
    #pragma unroll
    for (int ii = 0; ii < 4; ++ii)
        #pragma unroll
        for (int jj = 0; jj < 4; ++jj) {
            int rg = wm * 64 + ii * 16 + quad * 4;
            int cg = wn * 64 + jj * 16 + m16;
            #pragma unroll
            for (int r = 0; r < 4; ++r)
                Gb[(rg + r) * 128 + cg] = acc[ii][jj][r];
        }
}

// ---------------- kernel 2b: fold triangle partials + mirror ----------
__global__ __launch_bounds__(256) void k_fold_tri(const float* __restrict__ Gp,
                                                  float* __restrict__ G) {
    int t = blockIdx.x;       // 0..35 upper-triangle tile index
    int panel = blockIdx.y;   // 0..3: 32-row panel within the tile
    int bi = 0, rem = t;
    while (rem >= 8 - bi) { rem -= 8 - bi; ++bi; }
    int bj = bi + rem;
    bool diag = (bi == bj);
    int tid = threadIdx.x;

    const float* P = Gp + (((size_t)t * NKS) << 14) + panel * 4096;

    float4 s[4];
    #pragma unroll
    for (int m = 0; m < 4; ++m)
        s[m] = *(const float4*)(P + (tid + 256 * m) * 4);
    #pragma unroll
    for (int p = 1; p < NKS; ++p) {
        const float* Pp = P + (((size_t)p) << 14);
        #pragma unroll
        for (int m = 0; m < 4; ++m) {
            float4 v = *(const float4*)(Pp + (tid + 256 * m) * 4);
            s[m].x += v.x; s[m].y += v.y; s[m].z += v.z; s[m].w += v.w;
        }
    }

    int i0 = bi * 128, j0 = bj * 128, r0 = panel * 32;
    __shared__ float ts[32][129];
    #pragma unroll
    for (int m = 0; m < 4; ++m) {
        int p4 = (tid + 256 * m) * 4;
        int lr = p4 >> 7, lc = p4 & 127;
        *(float4*)(&G[(size_t)(i0 + r0 + lr) * NSAMP + j0 + lc]) = s[m];
        if (!diag) {
            ts[lr][lc] = s[m].x; ts[lr][lc + 1] = s[m].y;
            ts[lr][lc + 2] = s[m].z; ts[lr][lc + 3] = s[m].w;
        }
    }
    if (diag) return;
    __syncthreads();
    int oc = tid >> 1, half = tid & 1;
    float4 o[4];
    #pragma unroll
    for (int k = 0; k < 4; ++k) {
        int rr = half * 16 + k * 4;
        o[k].x = ts[rr][oc]; o[k].y = ts[rr + 1][oc];
        o[k].z = ts[rr + 2][oc]; o[k].w = ts[rr + 3][oc];
    }
    float* Gm = &G[(size_t)(j0 + oc) * NSAMP + i0 + r0 + half * 16];
    #pragma unroll
    for (int k = 0; k < 4; ++k) *(float4*)(Gm + k * 4) = o[k];
}

// ------- kernel 3: select + ambiguity flagging + fused exact re-rank -------
__global__ __launch_bounds__(256) void k_select_fix(const float* __restrict__ G,
                                                    const float* __restrict__ sq,
                                                    const int* __restrict__ tgt,
                                                    const float* __restrict__ x,
                                                    const ushort_t* __restrict__ xhi,
                                                    int* __restrict__ hp,
                                                    int* __restrict__ hn,
                                                    float* __restrict__ dsq) {
    int i = blockIdx.x;
    int tid = threadIdx.x;
    float sqi = sq[i];
    int ti = tgt[i];
    float dloc[4]; bool sloc[4];
    float pv = -3.0e38f; int pj = 0x7FFFFFFF;
    float nv = 3.0e38f;  int nj = 0x7FFFFFFF;
    #pragma unroll
    for (int m = 0; m < 4; ++m) {
        int j = tid + 256 * m;
        float g = G[(size_t)i * NSAMP + j];
        float d = sqrtf(fmaxf(sqi + sq[j] - 2.f * g, 1e-12f));
        bool same = (tgt[j] == ti);
        dloc[m] = d; sloc[m] = same;
        float cp = same ? d : -1e30f;
        float cn = same ? 1e30f : d;
        if (cp > pv || (cp == pv && j < pj)) { pv = cp; pj = j; }
        if (cn < nv || (cn == nv && j < nj)) { nv = cn; nj = j; }
    }
    for (int off = 32; off; off >>= 1) {
        float opv = __shfl_down(pv, off, 64); int opj = __shfl_down(pj, off, 64);
        float onv = __shfl_down(nv, off, 64); int onj = __shfl_down(nj, off, 64);
        if (opv > pv || (opv == pv && opj < pj)) { pv = opv; pj = opj; }
        if (onv < nv || (onv == nv && onj < nj)) { nv = onv; nj = onj; }
    }
    __shared__ float spv[4], snv[4];
    __shared__ int spj[4], snj[4];
    __shared__ float bb[2];
    __shared__ int cc[2];
    if ((tid & 63) == 0) { int wv = tid >> 6; spv[wv] = pv; spj[wv] = pj; snv[wv] = nv; snj[wv] = nj; }
    __syncthreads();
    if (tid == 0) {
        for (int wv = 1; wv < 4; ++wv) {
            if (spv[wv] > pv || (spv[wv] == pv && spj[wv] < pj)) { pv = spv[wv]; pj = spj[wv]; }
            if (snv[wv] < nv || (snv[wv] == nv && snj[wv] < nj)) { nv = snv[wv]; nj = snj[wv]; }
        }
        hp[i] = pj; hn[i] = nj;
        dsq[i] = sqi; dsq[NSAMP + i] = sqi;   // ||A||^2 init for k_dc
        bb[0] = pv; bb[1] = nv;
        cc[0] = 0; cc[1] = 0;
    }
    __syncthreads();
    {
        int lp = 0, ln = 0;
        #pragma unroll
        for (int m = 0; m < 4; ++m) {
            if (sloc[m] && dloc[m] >= bb[0] - MARG) lp++;
            if (!sloc[m] && dloc[m] <= bb[1] + MARG) ln++;
        }
        if (lp) atomicAdd(&cc[0], lp);
        if (ln) atomicAdd(&cc[1], ln);
    }
    __syncthreads();

    __shared__ int cand[32];
    __shared__ int ncand;
    __shared__ float bred[4];
    const float* xi = x + (size_t)i * D;
    const ushort_t* hi = xhi + (size_t)i * D;
    for (int type = 0; type < 2; ++type) {
        if (cc[type] <= 1) continue;          // block-uniform (shared)
        if (tid == 0) ncand = 0;
        __syncthreads();
        float bd = bb[type];
        #pragma unroll
        for (int m = 0; m < 4; ++m) {
            int j = tid + 256 * m;
            bool fl = (type == 0) ? (sloc[m] && dloc[m] >= bd - MARG)
                                  : (!sloc[m] && dloc[m] <= bd + MARG);
            if (fl) { int k = atomicAdd(&ncand, 1); if (k < 32) cand[k] = j; }
        }
        __syncthreads();
        int nc = ncand < 32 ? ncand : 32;
        float bestv = (type == 0) ? -3.0e38f : 3.0e38f;
        int bestj = 0x7FFFFFFF;
        for (int c = 0; c < nc; ++c) {
            int j = cand[c];
            const float* xj = x + (size_t)j * D;
            const ushort_t* hj = xhi + (size_t)j * D;
            float corr = 0.f;
            #pragma unroll
            for (int m = 0; m < 16; ++m) {
                int k = m * 1024 + tid * 4;
                float4 xa = *(const float4*)(xi + k);
                float4 xb = *(const float4*)(xj + k);
                ushort4 ha = *(const ushort4*)(hi + k);
                ushort4 hb = *(const ushort4*)(hj + k);
                float a0 = bf2f(ha.x), a1 = bf2f(ha.y), a2 = bf2f(ha.z), a3 = bf2f(ha.w);
                float b0 = bf2f(hb.x), b1 = bf2f(hb.y), b2 = bf2f(hb.z), b3 = bf2f(hb.w);
                corr += a0 * (xb.x - b0) + (xa.x - a0) * b0;
                corr += a1 * (xb.y - b1) + (xa.y - a1) * b1;
                corr += a2 * (xb.z - b2) + (xa.z - a2) * b2;
                corr += a3 * (xb.w - b3) + (xa.w - a3) * b3;
            }
            for (int off = 32; off; off >>= 1) corr += __shfl_down(corr, off, 64);
            if ((tid & 63) == 0) bred[tid >> 6] = corr;
            __syncthreads();
            float cs = bred[0] + bred[1] + bred[2] + bred[3];
            float g = G[(size_t)i * NSAMP + j];
            float d2 = sqi + sq[j] - 2.f * (g + cs);
            float d = sqrtf(fmaxf(d2, 1e-12f));
            if (type == 0) {
                if (d > bestv || (d == bestv && j < bestj)) { bestv = d; bestj = j; }
            } else {
                if (d < bestv || (d == bestv && j < bestj)) { bestv = d; bestj = j; }
            }
            __syncthreads();
        }
        if (tid == 0 && nc > 0) { if (type == 0) hp[i] = bestj; else hn[i] = bestj; }
        __syncthreads();
    }
}

// ---------------- kernel 4: DC align via MFMA (q-merged, async-staged) ----
// grid (b, which) = 2048 blocks. Each wave handles TWO 16-row tiles
// (rt = wv, wv+4): O stage + O transpose once per block, O/Ot fragment
// ds_reads shared across both halves. O staged via global_load_lds with
// PRE-SWIZZLED SOURCE (HW-verified in R7): LDS dest linear (granule p ->
// byte p*16), source granule is the lds_off inverse (s ^ (row&15)) -- zero
// staging registers / ds_writes. Cross-block overlap hides stage latency
// (R7 proved the serial which-loop exposes it: 55 us, occ 9.8%).
__global__ __launch_bounds__(256) void k_dc_mfma(const ushort_t* __restrict__ xhi,
                                                 const int* __restrict__ hp,
                                                 const int* __restrict__ hn,
                                                 float* __restrict__ dsq) {
    int b = blockIdx.x;
    int which = blockIdx.y;
    int oidx = (which == 0) ? hp[b] : hn[b];
    const ushort_t* Ag = xhi + (size_t)b * D;
    const ushort_t* Og = xhi + (size_t)oidx * D;

    __shared__ __align__(16) char smem[32768];   // O, then Ot in place

    int tid = threadIdx.x;
    int wv = tid >> 6, lane = tid & 63;
    int quad = lane >> 4, m16 = lane & 15;

    // Pre-swizzled async O staging: granule p = tid + 256*k; LDS dest
    // linear p*16; source element (p>>4)*128 + ((p&15)^((p>>4)&15))*8.
    #pragma unroll
    for (int k = 0; k < 8; ++k) {
        int p = tid + 256 * k;
        int row = p >> 4, s = p & 15;
        gload_lds16(Og + row * 128 + ((s ^ (row & 15)) << 3), smem + p * 16);
    }

    bf16x8 af[2][4];
    #pragma unroll
    for (int h = 0; h < 2; ++h) {
        int rt = h * 4 + wv;
        #pragma unroll
        for (int ks = 0; ks < 4; ++ks)
            af[h][ks] = *(const bf16x8*)(Ag + (rt * 16 + m16) * WH + ks * 32 + quad * 8);
    }
    __syncthreads();   // B1: O staged (syncthreads drains vmcnt)

    f32x4 acc[2][8];
    #pragma unroll
    for (int h = 0; h < 2; ++h)
        #pragma unroll
        for (int ti = 0; ti < 8; ++ti)
            acc[h][ti] = (f32x4){0.f, 0.f, 0.f, 0.f};
    #pragma unroll
    for (int ks = 0; ks < 4; ++ks) {
        bf16x8 of[8];
        #pragma unroll
        for (int ti = 0; ti < 8; ++ti)
            of[ti] = *(const bf16x8*)(smem + lds_off(ti * 16 + m16, (ks * 4 + quad) * 8));
        __builtin_amdgcn_s_setprio(1);
        #pragma unroll
        for (int h = 0; h < 2; ++h)
            #pragma unroll
            for (int ti = 0; ti < 8; ++ti)
                acc[h][ti] = __builtin_amdgcn_mfma_f32_16x16x32_bf16(of[ti], af[h][ks], acc[h][ti], 0, 0, 0);
        __builtin_amdgcn_s_setprio(0);
    }

    int c0 = (tid & 31) * 4, h0 = (tid >> 5) * 16;
    uint4 trd[4][2];
    #pragma unroll
    for (int j = 0; j < 4; ++j)
        #pragma unroll
        for (int k = 0; k < 2; ++k)
            trd[j][k] = *(const uint4*)(smem + lds_off(c0 + j, h0 + 8 * k));
    __syncthreads();   // B2: all O reads done

    #pragma unroll
    for (int i = 0; i < 16; ++i) {
        uint v[4];
        #pragma unroll
        for (int j = 0; j < 4; ++j) {
            uint wo = ((const uint*)&trd[j][i >> 3])[(i >> 1) & 3];
            v[j] = (i & 1) ? (wo >> 16) : (wo & 0xffffu);
        }
        uint2 pk;
        pk.x = v[0] | (v[1] << 16);
        pk.y = v[2] | (v[3] << 16);
        *(uint2*)(smem + lds_off(h0 + i, c0)) = pk;
    }

    float tpart[2];
    bf16x8 pf[2][4];
    #pragma unroll
    for (int h = 0; h < 2; ++h) {
        float mx = -3.0e38f;
        #pragma unroll
        for (int ti = 0; ti < 8; ++ti)
            #pragma unroll
            for (int r = 0; r < 4; ++r) {
                float s = acc[h][ti][r] * SCALE;
                acc[h][ti][r] = s;
                mx = fmaxf(mx, s);
            }
        mx = fmaxf(mx, __shfl_xor(mx, 16, 64));
        mx = fmaxf(mx, __shfl_xor(mx, 32, 64));
        float sum = 0.f, tnum = 0.f;
        #pragma unroll
        for (int ti = 0; ti < 8; ++ti)
            #pragma unroll
            for (int r = 0; r < 4; ++r) {
                float s = acc[h][ti][r];
                float e = __expf(s - mx);
                acc[h][ti][r] = e;
                sum += e;
                tnum += s * e;
            }
        sum += __shfl_xor(sum, 16, 64);
        sum += __shfl_xor(sum, 32, 64);
        tnum += __shfl_xor(tnum, 16, 64);
        tnum += __shfl_xor(tnum, 32, 64);
        float inv = 1.f / sum;
        tpart[h] = 0.25f * tnum * inv;

        uint Ep[8][2];
        #pragma unroll
        for (int ti = 0; ti < 8; ++ti) {
            Ep[ti][0] = (uint)f2bf(acc[h][ti][0] * inv) |
                        ((uint)f2bf(acc[h][ti][1] * inv) << 16);
            Ep[ti][1] = (uint)f2bf(acc[h][ti][2] * inv) |
                        ((uint)f2bf(acc[h][ti][3] * inv) << 16);
        }
        int tih = quad >> 1;
        #pragma unroll
        for (int ks = 0; ks < 4; ++ks) {
            union { uint u[4]; bf16x8 v; } fr;
            #pragma unroll
            for (int k = 0; k < 4; ++k) {
                int src = (((quad << 1) + (k >> 1)) & 3) * 16 + m16;
                int a = __shfl((int)Ep[2 * ks + 0][k & 1], src, 64);
                int bsh = __shfl((int)Ep[2 * ks + 1][k & 1], src, 64);
                fr.u[k] = (uint)((tih == 0) ? a : bsh);
            }
            pf[h][ks] = fr.v;
        }
    }
    __syncthreads();   // B3: Ot complete

    #pragma unroll
    for (int h = 0; h < 2; ++h)
        #pragma unroll
        for (int tj = 0; tj < 8; ++tj)
            acc[h][tj] = (f32x4){0.f, 0.f, 0.f, 0.f};
    #pragma unroll
    for (int ks = 0; ks < 4; ++ks) {
        bf16x8 otf[8];
        #pragma unroll
        for (int tj = 0; tj < 8; ++tj)
            otf[tj] = *(const bf16x8*)(smem + lds_off(tj * 16 + m16, (ks * 4 + quad) * 8));
        __builtin_amdgcn_s_setprio(1);
        #pragma unroll
        for (int h = 0; h < 2; ++h)
            #pragma unroll
            for (int tj = 0; tj < 8; ++tj)
                acc[h][tj] = __builtin_amdgcn_mfma_f32_16x16x32_bf16(pf[h][ks], otf[tj], acc[h][tj], 0, 0, 0);
        __builtin_amdgcn_s_setprio(0);
    }

    float part = 0.f;
    #pragma unroll
    for (int h = 0; h < 2; ++h) {
        float m2 = 0.f;
        #pragma unroll
        for (int tj = 0; tj < 8; ++tj)
            #pragma unroll
            for (int r = 0; r < 4; ++r) {
                float mvv = acc[h][tj][r];
                m2 += mvv * mvv;
            }
        part += m2 - 2.f * RSCALE * tpart[h];
    }
    for (int off = 32; off; off >>= 1) part += __shfl_down(part, off, 64);
    if (lane == 0) atomicAdd(&dsq[which * NSAMP + b], part);
}

// ---------------- kernel 5: final loss ----------------
__global__ void k_loss(const float* __restrict__ dsq, float* __restrict__ out) {
    int tid = threadIdx.x;
    float s = 0.f;
    #pragma unroll
    for (int m = 0; m < 4; ++m) {
        int b = tid + 256 * m;
        float ap = sqrtf(fmaxf(dsq[b], 0.f));
        float an = sqrtf(fmaxf(dsq[NSAMP + b], 0.f));
        s += fmaxf(ap - an + MARGIN, 0.f);
    }
    for (int off = 32; off; off >>= 1) s += __shfl_down(s, off, 64);
    __shared__ float red[4];
    if ((tid & 63) == 0) red[tid >> 6] = s;
    __syncthreads();
    if (tid == 0) out[0] = (red[0] + red[1] + red[2] + red[3]) * (1.f / NSAMP);
}

extern "C" void kernel_launch(void* const* d_in, const int* in_sizes, int n_in,
                              void* d_out, int out_size, void* d_ws, size_t ws_size,
                              hipStream_t stream) {
    const float* x = (const float*)d_in[0];
    const int* tgt = (const int*)d_in[1];
    float* out = (float*)d_out;
    char* ws = (char*)d_ws;

    const size_t GPB = (size_t)NTILE * NKS * 65536;  // 36 MB triangle partials
    const size_t XB = (size_t)NSAMP * D * 2;         // 32 MB (xhi)
    const size_t GB1 = (size_t)NSAMP * NSAMP * 4;    // 4 MB G

    float* Gp = (float*)ws;                               // 36 MB
    ushort_t* xhi = (ushort_t*)(ws + GPB);                // 32 MB
    float* G = (float*)(ws + GPB + XB);                   // 4 MB
    char* tail = ws + GPB + XB + GB1;
    float* sq = (float*)tail;                             // 4 KB
    float* dsq = sq + NSAMP;                              // 8 KB
    int* hp = (int*)(dsq + 2 * NSAMP);                    // 4 KB
    int* hn = hp + NSAMP;                                 // 4 KB

    k_norms_hi<<<NSAMP, 256, 0, stream>>>(x, sq, xhi);
    k_gram_hi<<<NKS * NTILE, 256, 0, stream>>>(xhi, Gp);
    k_fold_tri<<<dim3(NTILE, 4), 256, 0, stream>>>(Gp, G);
    k_select_fix<<<NSAMP, 256, 0, stream>>>(G, sq, tgt, x, xhi, hp, hn, dsq);
    k_dc_mfma<<<dim3(NSAMP, 2), 256, 0, stream>>>(xhi, hp, hn, dsq);
    k_loss<<<1, 256, 0, stream>>>(dsq, out);
}

// Round 9
// 192.219 us; speedup vs baseline: 1.0762x; 1.0104x over previous
//
#include <hip/hip_runtime.h>
#include <stdint.h>

#define NSAMP 1024
#define D 16384
#define WH 128
#define MARGIN 0.3f
#define SCALE 0.08838834764831845f    // 1/sqrt(128)
#define RSCALE 11.313708498984761f    // sqrt(128)
#define MARG 0.03f                    // selection ambiguity margin (d units)
#define NKS 16                        // uniform K-slices per tile (K=1024 each)
#define NTILE 36                      // upper-triangle 128x128 tiles of 8x8 grid

typedef unsigned int uint;
typedef unsigned short ushort_t;

typedef __attribute__((ext_vector_type(8))) short bf16x8;   // 8 bf16 = 4 VGPRs
typedef __attribute__((ext_vector_type(4))) float f32x4;

__device__ __forceinline__ float bf2f(unsigned short b) {
    return __uint_as_float(((uint)b) << 16);
}
__device__ __forceinline__ unsigned short f2bf(float f) {
    uint u = __float_as_uint(f);
    u += 0x7fffu + ((u >> 16) & 1u);   // RNE (data has no NaN)
    return (unsigned short)(u >> 16);
}
__device__ __forceinline__ void gload_lds16(const void* g, void* l) {
    __builtin_amdgcn_global_load_lds(
        (const __attribute__((address_space(1))) uint32_t*)g,
        (__attribute__((address_space(3))) uint32_t*)l, 16, 0, 0);
}
// Swizzled LDS byte offset for a 128-col bf16 row-major tile (k_dc_mfma).
__device__ __forceinline__ int lds_off(int row, int col) {
    return row * 256 + ((((col >> 3) ^ (row & 15)) << 4) | ((col & 7) << 1));
}

// ---------------- kernel 1: row norms (fp32) + hi bf16 cast ----------------
__global__ __launch_bounds__(256) void k_norms_hi(const float* __restrict__ x,
                                                  float* __restrict__ sq,
                                                  ushort_t* __restrict__ xhi) {
    int b = blockIdx.x;
    int tid = threadIdx.x;
    const float* xr = x + (size_t)b * D;
    ushort_t* hr = xhi + (size_t)b * D;
    float s = 0.f;
    #pragma unroll
    for (int m = 0; m < 16; ++m) {
        int e = m * 1024 + tid * 4;
        float4 v = *(const float4*)(xr + e);
        s += v.x * v.x + v.y * v.y + v.z * v.z + v.w * v.w;
        ushort4 h;
        h.x = f2bf(v.x); h.y = f2bf(v.y); h.z = f2bf(v.z); h.w = f2bf(v.w);
        *(ushort4*)(hr + e) = h;
    }
    for (int off = 32; off; off >>= 1) s += __shfl_down(s, off, 64);
    __shared__ float red[4];
    if ((tid & 63) == 0) red[tid >> 6] = s;
    __syncthreads();
    if (tid == 0) sq[b] = red[0] + red[1] + red[2] + red[3];
}

// ---------------- kernel 2: G~ = Hi.Hi^T partials via MFMA ----------------
// FROZEN: R2 2-barrier structure + XCD-aware flat decode + T5 setprio.
// R3/R4/R5 proved deeper pipelines / counted-vmcnt all regress here.
__global__ __launch_bounds__(256) void k_gram_hi(const ushort_t* __restrict__ xhi,
                                                 float* __restrict__ Gp) {
    int n = blockIdx.x;
    int r8 = n & 7;
    int m = n >> 3;                 // 0..71 = 36*h + t
    int h = m / 36;                 // 0 or 1
    int t = m - 36 * h;             // 0..35
    int ks = r8 + 8 * h;            // 0..15
    int bi = 0, rem = t;
    while (rem >= 8 - bi) { rem -= 8 - bi; ++bi; }
    int bj = bi + rem;
    int i0 = bi * 128, j0 = bj * 128;
    int kstart = ks * (D / NKS);

    int tid = threadIdx.x;
    int w = tid >> 6, lane = tid & 63;
    int wm = w & 1, wn = w >> 1;
    int quad = lane >> 4, m16 = lane & 15;
    int srow = lane >> 2, sseg = lane & 3;
    int swseg = sseg ^ ((srow >> 1) & 3);          // pre-swizzled source seg
    int rsw = (quad ^ ((m16 >> 1) & 3)) << 3;      // lane-constant read seg

    __shared__ __align__(16) ushort_t A_s[2][128 * 32];   // 16 KB
    __shared__ __align__(16) ushort_t B_s[2][128 * 32];   // 16 KB

    f32x4 acc[4][4];
    #pragma unroll
    for (int ii = 0; ii < 4; ++ii)
        #pragma unroll
        for (int jj = 0; jj < 4; ++jj)
            acc[ii][jj] = (f32x4){0.f, 0.f, 0.f, 0.f};

    const size_t Abase = (size_t)i0 * D;
    const size_t Bbase = (size_t)j0 * D;

    auto stage = [&](int bsel, int k0) {
        #pragma unroll
        for (int c = 0; c < 2; ++c) {
            int r = w * 32 + c * 16 + srow;
            size_t go = (size_t)r * D + k0 + swseg * 8;
            int lo = (w * 32 + c * 16) * 32;
            gload_lds16(xhi + Abase + go, &A_s[bsel][lo]);
            gload_lds16(xhi + Bbase + go, &B_s[bsel][lo]);
        }
    };
    auto compute = [&](int bsel) {
        bf16x8 ah[4], bh[4];
        #pragma unroll
        for (int ii = 0; ii < 4; ++ii) {
            int ar = wm * 64 + ii * 16 + m16;
            ah[ii] = *(const bf16x8*)&A_s[bsel][ar * 32 + rsw];
        }
        #pragma unroll
        for (int jj = 0; jj < 4; ++jj) {
            int br = wn * 64 + jj * 16 + m16;
            bh[jj] = *(const bf16x8*)&B_s[bsel][br * 32 + rsw];
        }
        __builtin_amdgcn_s_setprio(1);
        #pragma unroll
        for (int ii = 0; ii < 4; ++ii)
            #pragma unroll
            for (int jj = 0; jj < 4; ++jj)
                acc[ii][jj] = __builtin_amdgcn_mfma_f32_16x16x32_bf16(ah[ii], bh[jj], acc[ii][jj], 0, 0, 0);
        __builtin_amdgcn_s_setprio(0);
    };

    stage(0, kstart);
    __syncthreads();
    int buf = 0;
    for (int kb = 0; kb < 32; ++kb) {
        if (kb < 31) stage(buf ^ 1, kstart + (kb + 1) * 32);
        compute(buf);
        __syncthreads();
        buf ^= 1;
    }

    // Uniform partial slot: tile-major so fold reads 1 MB contiguous/tile.
    float* Gb = Gp + ((size_t)(t * NKS + ks) << 14);
    #pragma unroll
    for (int ii = 0; ii < 4; ++ii)
        #pragma unroll
        for (int jj = 0; jj < 4; ++jj) {
            int rg = wm * 64 + ii * 16 + quad * 4;
            int cg = wn * 64 + jj * 16 + m16;
            #pragma unroll
            for (int r = 0; r < 4; ++r)
                Gb[(rg + r) * 128 + cg] = acc[ii][jj][r];
        }
}

// ---------------- kernel 2b: fold triangle partials + mirror ----------
__global__ __launch_bounds__(256) void k_fold_tri(const float* __restrict__ Gp,
                                                  float* __restrict__ G) {
    int t = blockIdx.x;       // 0..35 upper-triangle tile index
    int panel = blockIdx.y;   // 0..3: 32-row panel within the tile
    int bi = 0, rem = t;
    while (rem >= 8 - bi) { rem -= 8 - bi; ++bi; }
    int bj = bi + rem;
    bool diag = (bi == bj);
    int tid = threadIdx.x;

    const float* P = Gp + (((size_t)t * NKS) << 14) + panel * 4096;

    float4 s[4];
    #pragma unroll
    for (int m = 0; m < 4; ++m)
        s[m] = *(const float4*)(P + (tid + 256 * m) * 4);
    #pragma unroll
    for (int p = 1; p < NKS; ++p) {
        const float* Pp = P + (((size_t)p) << 14);
        #pragma unroll
        for (int m = 0; m < 4; ++m) {
            float4 v = *(const float4*)(Pp + (tid + 256 * m) * 4);
            s[m].x += v.x; s[m].y += v.y; s[m].z += v.z; s[m].w += v.w;
        }
    }

    int i0 = bi * 128, j0 = bj * 128, r0 = panel * 32;
    __shared__ float ts[32][129];
    #pragma unroll
    for (int m = 0; m < 4; ++m) {
        int p4 = (tid + 256 * m) * 4;
        int lr = p4 >> 7, lc = p4 & 127;
        *(float4*)(&G[(size_t)(i0 + r0 + lr) * NSAMP + j0 + lc]) = s[m];
        if (!diag) {
            ts[lr][lc] = s[m].x; ts[lr][lc + 1] = s[m].y;
            ts[lr][lc + 2] = s[m].z; ts[lr][lc + 3] = s[m].w;
        }
    }
    if (diag) return;
    __syncthreads();
    int oc = tid >> 1, half = tid & 1;
    float4 o[4];
    #pragma unroll
    for (int k = 0; k < 4; ++k) {
        int rr = half * 16 + k * 4;
        o[k].x = ts[rr][oc]; o[k].y = ts[rr + 1][oc];
        o[k].z = ts[rr + 2][oc]; o[k].w = ts[rr + 3][oc];
    }
    float* Gm = &G[(size_t)(j0 + oc) * NSAMP + i0 + r0 + half * 16];
    #pragma unroll
    for (int k = 0; k < 4; ++k) *(float4*)(Gm + k * 4) = o[k];
}

// ------- kernel 3: select + ambiguity flagging + fused exact re-rank -------
__global__ __launch_bounds__(256) void k_select_fix(const float* __restrict__ G,
                                                    const float* __restrict__ sq,
                                                    const int* __restrict__ tgt,
                                                    const float* __restrict__ x,
                                                    const ushort_t* __restrict__ xhi,
                                                    int* __restrict__ hp,
                                                    int* __restrict__ hn,
                                                    float* __restrict__ dsq) {
    int i = blockIdx.x;
    int tid = threadIdx.x;
    float sqi = sq[i];
    int ti = tgt[i];
    float dloc[4]; bool sloc[4];
    float pv = -3.0e38f; int pj = 0x7FFFFFFF;
    float nv = 3.0e38f;  int nj = 0x7FFFFFFF;
    #pragma unroll
    for (int m = 0; m < 4; ++m) {
        int j = tid + 256 * m;
        float g = G[(size_t)i * NSAMP + j];
        float d = sqrtf(fmaxf(sqi + sq[j] - 2.f * g, 1e-12f));
        bool same = (tgt[j] == ti);
        dloc[m] = d; sloc[m] = same;
        float cp = same ? d : -1e30f;
        float cn = same ? 1e30f : d;
        if (cp > pv || (cp == pv && j < pj)) { pv = cp; pj = j; }
        if (cn < nv || (cn == nv && j < nj)) { nv = cn; nj = j; }
    }
    for (int off = 32; off; off >>= 1) {
        float opv = __shfl_down(pv, off, 64); int opj = __shfl_down(pj, off, 64);
        float onv = __shfl_down(nv, off, 64); int onj = __shfl_down(nj, off, 64);
        if (opv > pv || (opv == pv && opj < pj)) { pv = opv; pj = opj; }
        if (onv < nv || (onv == nv && onj < nj)) { nv = onv; nj = onj; }
    }
    __shared__ float spv[4], snv[4];
    __shared__ int spj[4], snj[4];
    __shared__ float bb[2];
    __shared__ int cc[2];
    if ((tid & 63) == 0) { int wv = tid >> 6; spv[wv] = pv; spj[wv] = pj; snv[wv] = nv; snj[wv] = nj; }
    __syncthreads();
    if (tid == 0) {
        for (int wv = 1; wv < 4; ++wv) {
            if (spv[wv] > pv || (spv[wv] == pv && spj[wv] < pj)) { pv = spv[wv]; pj = spj[wv]; }
            if (snv[wv] < nv || (snv[wv] == nv && snj[wv] < nj)) { nv = snv[wv]; nj = snj[wv]; }
        }
        hp[i] = pj; hn[i] = nj;
        dsq[i] = sqi; dsq[NSAMP + i] = sqi;   // ||A||^2 init for k_dc
        bb[0] = pv; bb[1] = nv;
        cc[0] = 0; cc[1] = 0;
    }
    __syncthreads();
    {
        int lp = 0, ln = 0;
        #pragma unroll
        for (int m = 0; m < 4; ++m) {
            if (sloc[m] && dloc[m] >= bb[0] - MARG) lp++;
            if (!sloc[m] && dloc[m] <= bb[1] + MARG) ln++;
        }
        if (lp) atomicAdd(&cc[0], lp);
        if (ln) atomicAdd(&cc[1], ln);
    }
    __syncthreads();

    __shared__ int cand[32];
    __shared__ int ncand;
    __shared__ float bred[4];
    const float* xi = x + (size_t)i * D;
    const ushort_t* hi = xhi + (size_t)i * D;
    for (int type = 0; type < 2; ++type) {
        if (cc[type] <= 1) continue;          // block-uniform (shared)
        if (tid == 0) ncand = 0;
        __syncthreads();
        float bd = bb[type];
        #pragma unroll
        for (int m = 0; m < 4; ++m) {
            int j = tid + 256 * m;
            bool fl = (type == 0) ? (sloc[m] && dloc[m] >= bd - MARG)
                                  : (!sloc[m] && dloc[m] <= bd + MARG);
            if (fl) { int k = atomicAdd(&ncand, 1); if (k < 32) cand[k] = j; }
        }
        __syncthreads();
        int nc = ncand < 32 ? ncand : 32;
        float bestv = (type == 0) ? -3.0e38f : 3.0e38f;
        int bestj = 0x7FFFFFFF;
        for (int c = 0; c < nc; ++c) {
            int j = cand[c];
            const float* xj = x + (size_t)j * D;
            const ushort_t* hj = xhi + (size_t)j * D;
            float corr = 0.f;
            #pragma unroll
            for (int m = 0; m < 16; ++m) {
                int k = m * 1024 + tid * 4;
                float4 xa = *(const float4*)(xi + k);
                float4 xb = *(const float4*)(xj + k);
                ushort4 ha = *(const ushort4*)(hi + k);
                ushort4 hb = *(const ushort4*)(hj + k);
                float a0 = bf2f(ha.x), a1 = bf2f(ha.y), a2 = bf2f(ha.z), a3 = bf2f(ha.w);
                float b0 = bf2f(hb.x), b1 = bf2f(hb.y), b2 = bf2f(hb.z), b3 = bf2f(hb.w);
                corr += a0 * (xb.x - b0) + (xa.x - a0) * b0;
                corr += a1 * (xb.y - b1) + (xa.y - a1) * b1;
                corr += a2 * (xb.z - b2) + (xa.z - a2) * b2;
                corr += a3 * (xb.w - b3) + (xa.w - a3) * b3;
            }
            for (int off = 32; off; off >>= 1) corr += __shfl_down(corr, off, 64);
            if ((tid & 63) == 0) bred[tid >> 6] = corr;
            __syncthreads();
            float cs = bred[0] + bred[1] + bred[2] + bred[3];
            float g = G[(size_t)i * NSAMP + j];
            float d2 = sqi + sq[j] - 2.f * (g + cs);
            float d = sqrtf(fmaxf(d2, 1e-12f));
            if (type == 0) {
                if (d > bestv || (d == bestv && j < bestj)) { bestv = d; bestj = j; }
            } else {
                if (d < bestv || (d == bestv && j < bestj)) { bestv = d; bestj = j; }
            }
            __syncthreads();
        }
        if (tid == 0 && nc > 0) { if (type == 0) hp[i] = bestj; else hn[i] = bestj; }
        __syncthreads();
    }
}

// ---------- kernel 4: DC align via MFMA (8-wave, 1 tile/wave) -------------
// grid (b, which) = 2048 blocks x 512 threads. Wave wv handles row-tile
// rt = wv (one 16-row tile) -> per-wave state back to acc[8]+af[4] (~48
// VGPR of accumulator, R2 level) while the O stage + O transpose still run
// ONCE per block (R8's win). Transpose per-thread work halves (4 cols x
// 8 rows). Pre-swizzled gload_lds staging (HW-verified R7/R8): LDS dest
// linear, source granule = lds_off inverse.
__global__ __launch_bounds__(512) void k_dc_mfma(const ushort_t* __restrict__ xhi,
                                                 const int* __restrict__ hp,
                                                 const int* __restrict__ hn,
                                                 float* __restrict__ dsq) {
    int b = blockIdx.x;
    int which = blockIdx.y;
    int oidx = (which == 0) ? hp[b] : hn[b];
    const ushort_t* Ag = xhi + (size_t)b * D;
    const ushort_t* Og = xhi + (size_t)oidx * D;

    __shared__ __align__(16) char smem[32768];   // O, then Ot in place

    int tid = threadIdx.x;
    int wv = tid >> 6, lane = tid & 63;
    int quad = lane >> 4, m16 = lane & 15;

    // Pre-swizzled async O staging: granule p = tid + 512*k (k<4); LDS dest
    // linear p*16; source element (p>>4)*128 + ((p&15)^((p>>4)&15))*8.
    #pragma unroll
    for (int k = 0; k < 4; ++k) {
        int p = tid + 512 * k;
        int row = p >> 4, s = p & 15;
        gload_lds16(Og + row * 128 + ((s ^ (row & 15)) << 3), smem + p * 16);
    }

    bf16x8 af[4];
    #pragma unroll
    for (int ks = 0; ks < 4; ++ks)
        af[ks] = *(const bf16x8*)(Ag + (wv * 16 + m16) * WH + ks * 32 + quad * 8);
    __syncthreads();   // B1: O staged (syncthreads drains vmcnt)

    f32x4 acc[8];
    #pragma unroll
    for (int ti = 0; ti < 8; ++ti)
        acc[ti] = (f32x4){0.f, 0.f, 0.f, 0.f};
    #pragma unroll
    for (int ks = 0; ks < 4; ++ks) {
        bf16x8 of[8];
        #pragma unroll
        for (int ti = 0; ti < 8; ++ti)
            of[ti] = *(const bf16x8*)(smem + lds_off(ti * 16 + m16, (ks * 4 + quad) * 8));
        __builtin_amdgcn_s_setprio(1);
        #pragma unroll
        for (int ti = 0; ti < 8; ++ti)
            acc[ti] = __builtin_amdgcn_mfma_f32_16x16x32_bf16(of[ti], af[ks], acc[ti], 0, 0, 0);
        __builtin_amdgcn_s_setprio(0);
    }

    // 512-thread in-place transpose: thread handles O[c0..c0+3][h0..h0+7].
    int c0 = (tid & 31) * 4, h0 = (tid >> 5) * 8;   // tid>>5 in 0..15
    uint4 trd[4];
    #pragma unroll
    for (int j = 0; j < 4; ++j)
        trd[j] = *(const uint4*)(smem + lds_off(c0 + j, h0));
    __syncthreads();   // B2: all O reads done

    #pragma unroll
    for (int i = 0; i < 8; ++i) {
        uint v[4];
        #pragma unroll
        for (int j = 0; j < 4; ++j) {
            uint wo = ((const uint*)&trd[j])[i >> 1];
            v[j] = (i & 1) ? (wo >> 16) : (wo & 0xffffu);
        }
        uint2 pk;
        pk.x = v[0] | (v[1] << 16);
        pk.y = v[2] | (v[3] << 16);
        *(uint2*)(smem + lds_off(h0 + i, c0)) = pk;
    }

    float tpart;
    bf16x8 pf[4];
    {
        float mx = -3.0e38f;
        #pragma unroll
        for (int ti = 0; ti < 8; ++ti)
            #pragma unroll
            for (int r = 0; r < 4; ++r) {
                float s = acc[ti][r] * SCALE;
                acc[ti][r] = s;
                mx = fmaxf(mx, s);
            }
        mx = fmaxf(mx, __shfl_xor(mx, 16, 64));
        mx = fmaxf(mx, __shfl_xor(mx, 32, 64));
        float sum = 0.f, tnum = 0.f;
        #pragma unroll
        for (int ti = 0; ti < 8; ++ti)
            #pragma unroll
            for (int r = 0; r < 4; ++r) {
                float s = acc[ti][r];
                float e = __expf(s - mx);
                acc[ti][r] = e;
                sum += e;
                tnum += s * e;
            }
        sum += __shfl_xor(sum, 16, 64);
        sum += __shfl_xor(sum, 32, 64);
        tnum += __shfl_xor(tnum, 16, 64);
        tnum += __shfl_xor(tnum, 32, 64);
        float inv = 1.f / sum;
        tpart = 0.25f * tnum * inv;

        uint Ep[8][2];
        #pragma unroll
        for (int ti = 0; ti < 8; ++ti) {
            Ep[ti][0] = (uint)f2bf(acc[ti][0] * inv) |
                        ((uint)f2bf(acc[ti][1] * inv) << 16);
            Ep[ti][1] = (uint)f2bf(acc[ti][2] * inv) |
                        ((uint)f2bf(acc[ti][3] * inv) << 16);
        }
        int tih = quad >> 1;
        #pragma unroll
        for (int ks = 0; ks < 4; ++ks) {
            union { uint u[4]; bf16x8 v; } fr;
            #pragma unroll
            for (int k = 0; k < 4; ++k) {
                int src = (((quad << 1) + (k >> 1)) & 3) * 16 + m16;
                int a = __shfl((int)Ep[2 * ks + 0][k & 1], src, 64);
                int bsh = __shfl((int)Ep[2 * ks + 1][k & 1], src, 64);
                fr.u[k] = (uint)((tih == 0) ? a : bsh);
            }
            pf[ks] = fr.v;
        }
    }
    __syncthreads();   // B3: Ot complete

    #pragma unroll
    for (int tj = 0; tj < 8; ++tj)
        acc[tj] = (f32x4){0.f, 0.f, 0.f, 0.f};
    #pragma unroll
    for (int ks = 0; ks < 4; ++ks) {
        bf16x8 otf[8];
        #pragma unroll
        for (int tj = 0; tj < 8; ++tj)
            otf[tj] = *(const bf16x8*)(smem + lds_off(tj * 16 + m16, (ks * 4 + quad) * 8));
        __builtin_amdgcn_s_setprio(1);
        #pragma unroll
        for (int tj = 0; tj < 8; ++tj)
            acc[tj] = __builtin_amdgcn_mfma_f32_16x16x32_bf16(pf[ks], otf[tj], acc[tj], 0, 0, 0);
        __builtin_amdgcn_s_setprio(0);
    }

    float m2 = 0.f;
    #pragma unroll
    for (int tj = 0; tj < 8; ++tj)
        #pragma unroll
        for (int r = 0; r < 4; ++r) {
            float mvv = acc[tj][r];
            m2 += mvv * mvv;
        }
    float part = m2 - 2.f * RSCALE * tpart;
    for (int off = 32; off; off >>= 1) part += __shfl_down(part, off, 64);
    if (lane == 0) atomicAdd(&dsq[which * NSAMP + b], part);
}

// ---------------- kernel 5: final loss ----------------
__global__ void k_loss(const float* __restrict__ dsq, float* __restrict__ out) {
    int tid = threadIdx.x;
    float s = 0.f;
    #pragma unroll
    for (int m = 0; m < 4; ++m) {
        int b = tid + 256 * m;
        float ap = sqrtf(fmaxf(dsq[b], 0.f));
        float an = sqrtf(fmaxf(dsq[NSAMP + b], 0.f));
        s += fmaxf(ap - an + MARGIN, 0.f);
    }
    for (int off = 32; off; off >>= 1) s += __shfl_down(s, off, 64);
    __shared__ float red[4];
    if ((tid & 63) == 0) red[tid >> 6] = s;
    __syncthreads();
    if (tid == 0) out[0] = (red[0] + red[1] + red[2] + red[3]) * (1.f / NSAMP);
}

extern "C" void kernel_launch(void* const* d_in, const int* in_sizes, int n_in,
                              void* d_out, int out_size, void* d_ws, size_t ws_size,
                              hipStream_t stream) {
    const float* x = (const float*)d_in[0];
    const int* tgt = (const int*)d_in[1];
    float* out = (float*)d_out;
    char* ws = (char*)d_ws;

    const size_t GPB = (size_t)NTILE * NKS * 65536;  // 36 MB triangle partials
    const size_t XB = (size_t)NSAMP * D * 2;         // 32 MB (xhi)
    const size_t GB1 = (size_t)NSAMP * NSAMP * 4;    // 4 MB G

    float* Gp = (float*)ws;                               // 36 MB
    ushort_t* xhi = (ushort_t*)(ws + GPB);                // 32 MB
    float* G = (float*)(ws + GPB + XB);                   // 4 MB
    char* tail = ws + GPB + XB + GB1;
    float* sq = (float*)tail;                             // 4 KB
    float* dsq = sq + NSAMP;                              // 8 KB
    int* hp = (int*)(dsq + 2 * NSAMP);                    // 4 KB
    int* hn = hp + NSAMP;                                 // 4 KB

    k_norms_hi<<<NSAMP, 256, 0, stream>>>(x, sq, xhi);
    k_gram_hi<<<NKS * NTILE, 256, 0, stream>>>(xhi, Gp);
    k_fold_tri<<<dim3(NTILE, 4), 256, 0, stream>>>(Gp, G);
    k_select_fix<<<NSAMP, 256, 0, stream>>>(G, sq, tgt, x, xhi, hp, hn, dsq);
    k_dc_mfma<<<dim3(NSAMP, 2), 512, 0, stream>>>(xhi, hp, hn, dsq);
    k_loss<<<1, 256, 0, stream>>>(dsq, out);
}